// Round 10
// baseline (718.936 us; speedup 1.0000x reference)
//
#include <hip/hip_runtime.h>
#include <hip/hip_bf16.h>
#include <stdint.h>

#define T_TOK 4096
#define DIMD  2048
#define NEXP  16
#define TOPK  4
#define NI    1024
#define NSH   2048

typedef __attribute__((ext_vector_type(8))) short short8;
typedef __attribute__((ext_vector_type(4))) float f32x4;
typedef __attribute__((ext_vector_type(4))) unsigned short u16x4;

__device__ __forceinline__ unsigned short f2bf(float f) {
    union { float f; unsigned u; } v; v.f = f;
    return (unsigned short)((v.u + 0x7fffu + ((v.u >> 16) & 1u)) >> 16);
}

__device__ __forceinline__ void gload16(const void* g, void* l) {
    __builtin_amdgcn_global_load_lds(
        (const __attribute__((address_space(1))) void*)g,
        (__attribute__((address_space(3))) void*)l, 16, 0, 0);
}

// ---------------- gw transpose ----------------
__global__ __launch_bounds__(256) void gwt_kernel(const float* __restrict__ gw,
                                                  float* __restrict__ gwT) {
    int i = blockIdx.x * 256 + threadIdx.x;
    int d = i >> 4, e = i & 15;
    gwT[e * DIMD + d] = gw[i];
}

// ---------------- gate: scores + top-4, LDS-histogram routing ----------------
__global__ __launch_bounds__(256) void gate_kernel(const float* __restrict__ x,
                                                   const float* __restrict__ gwT,
                                                   int* __restrict__ blk_cnt,
                                                   int* __restrict__ tk_er,
                                                   float* __restrict__ tk_wv) {
    __shared__ int h[16];
    const int blk = blockIdx.x;
    const int t = blk * 4 + (threadIdx.x >> 6);
    const int lane = threadIdx.x & 63;
    if (threadIdx.x < 16) h[threadIdx.x] = 0;
    __syncthreads();

    const f32x4* xr = (const f32x4*)(x + (size_t)t * DIMD);
    f32x4 xv[8];
#pragma unroll
    for (int i = 0; i < 8; ++i) xv[i] = xr[i * 64 + lane];

    float acc[NEXP];
#pragma unroll
    for (int e = 0; e < NEXP; ++e) {
        const f32x4* gr = (const f32x4*)(gwT + e * DIMD);
        float s = 0.f;
#pragma unroll
        for (int i = 0; i < 8; ++i) {
            f32x4 gv = gr[i * 64 + lane];
            s += xv[i][0] * gv[0] + xv[i][1] * gv[1] +
                 xv[i][2] * gv[2] + xv[i][3] * gv[3];
        }
        acc[e] = s;
    }
#pragma unroll
    for (int e = 0; e < NEXP; ++e) {
        float v = acc[e];
#pragma unroll
        for (int off = 32; off; off >>= 1) v += __shfl_xor(v, off, 64);
        acc[e] = v;
    }
    float m = acc[0];
#pragma unroll
    for (int e = 1; e < NEXP; ++e) m = fmaxf(m, acc[e]);
    float s = 0.f;
#pragma unroll
    for (int e = 0; e < NEXP; ++e) { acc[e] = expf(acc[e] - m); s += acc[e]; }
    float inv = 1.f / s;
#pragma unroll
    for (int e = 0; e < NEXP; ++e) acc[e] *= inv;

    float w4[TOPK]; int i4[TOPK];
#pragma unroll
    for (int k = 0; k < TOPK; ++k) {
        float bv = -1.f; int be = 0;
#pragma unroll
        for (int e = 0; e < NEXP; ++e)
            if (acc[e] > bv) { bv = acc[e]; be = e; }
        w4[k] = bv; i4[k] = be;
#pragma unroll
        for (int e = 0; e < NEXP; ++e)
            if (e == be) acc[e] = -1.f;
    }

    if (lane == 0) {
        int r4[TOPK];
#pragma unroll
        for (int k = 0; k < TOPK; ++k) r4[k] = atomicAdd(&h[i4[k]], 1);
#pragma unroll
        for (int k = 0; k < TOPK; ++k) {
            tk_er[t * 4 + k] = (i4[k] << 20) | r4[k];
            tk_wv[t * 4 + k] = w4[k];
        }
    }
    __syncthreads();
    if (threadIdx.x < 16) blk_cnt[blk * 16 + threadIdx.x] = h[threadIdx.x];
}

// ---------------- hierarchical scan; slot table at BM=128 ----------------
__global__ __launch_bounds__(256) void scan_kernel(const int* __restrict__ blk_cnt,
                                                   int* __restrict__ blk_off,
                                                   int* __restrict__ cnt,
                                                   int* __restrict__ offs,
                                                   int* __restrict__ table) {
    __shared__ int gsum[16][17];
    __shared__ int gbase[16][17];
    __shared__ int csh[16];
    int tid = threadIdx.x;
    int e = tid >> 4, g = tid & 15;
    {
        int s = 0;
        for (int b = g * 64; b < g * 64 + 64; ++b) s += blk_cnt[b * 16 + e];
        gsum[e][g] = s;
    }
    __syncthreads();
    if (tid < 16) {
        int run = 0;
        for (int g2 = 0; g2 < 16; ++g2) { gbase[tid][g2] = run; run += gsum[tid][g2]; }
        csh[tid] = run;
        cnt[tid] = run;
    }
    __syncthreads();
    {
        int run = gbase[e][g];
        for (int b = g * 64; b < g * 64 + 64; ++b) {
            blk_off[b * 16 + e] = run;
            run += blk_cnt[b * 16 + e];
        }
    }
    if (tid == 0) {
        int o = 0;
        for (int e2 = 0; e2 < 16; ++e2) { offs[e2] = o; o += csh[e2]; }
        offs[NEXP] = o;
        int ns = 0;
        for (int e2 = 0; e2 < 16; ++e2)
            for (int rb = 0; rb < csh[e2]; rb += 128) {
                table[ns] = (e2 << 16) | rb; ++ns;
            }
        table[255] = ns;
    }
}

// ---------------- fill compacted expert lists ----------------
__global__ __launch_bounds__(256) void fill_kernel(const int* __restrict__ tk_er,
                                                   const float* __restrict__ tk_wv,
                                                   const int* __restrict__ blk_off,
                                                   int* __restrict__ list,
                                                   float* __restrict__ cw) {
    int i = blockIdx.x * 256 + threadIdx.x;
    int rec = tk_er[i];
    int e = rec >> 20, r = rec & 0xFFFFF;
    int t = i >> 2;
    int ro = blk_off[(t >> 2) * 16 + e] + r;
    list[e * T_TOK + ro] = t;
    cw[e * T_TOK + ro] = tk_wv[i];
}

// ---------------- x fp32 -> bf16 ----------------
__global__ __launch_bounds__(256) void cvt_kernel(const float* __restrict__ x,
                                                  unsigned short* __restrict__ xb) {
    int i = blockIdx.x * 256 + threadIdx.x;
    const f32x4* src = (const f32x4*)x;
    f32x4 a = src[i * 2 + 0];
    f32x4 b = src[i * 2 + 1];
    short8 o;
#pragma unroll
    for (int j = 0; j < 4; ++j) o[j] = (short)f2bf(a[j]);
#pragma unroll
    for (int j = 0; j < 4; ++j) o[4 + j] = (short)f2bf(b[j]);
    ((short8*)xb)[i] = o;
}

// ---------------- weight transpose + convert ----------------
template <int MODE>
__global__ __launch_bounds__(256) void tq_kernel(const float* __restrict__ src,
                                                 unsigned short* __restrict__ dst,
                                                 int K, int N, size_t dstStrideE) {
    int e = blockIdx.z;
    src += (size_t)e * K * N;
    dst += (size_t)e * dstStrideE;
    __shared__ unsigned short tile[32][36];
    int t = threadIdx.x;
    int k0 = blockIdx.y * 32, n0 = blockIdx.x * 32;
    {
        int row = t >> 3, c4 = (t & 7) * 4;
        f32x4 v = *(const f32x4*)(src + (size_t)(k0 + row) * N + n0 + c4);
#pragma unroll
        for (int j = 0; j < 4; ++j) tile[row][c4 + j] = f2bf(v[j]);
    }
    __syncthreads();
    {
        int nn = t >> 3, kc = (t & 7) * 4;
        int n = n0 + nn;
        int r = (MODE == 0) ? n : ((n >> 4) * 32 + (MODE == 2 ? 16 : 0) + (n & 15));
        u16x4 o;
#pragma unroll
        for (int j = 0; j < 4; ++j) o[j] = tile[kc + j][nn];
        *(u16x4*)(dst + (size_t)r * K + k0 + kc) = o;
    }
}

// ======== 128x256 GEMM, 4 waves (wave-tile 128x64), BK=32, 2 blocks/CU ========
// LDS 72KB/block: A 3x8KB at 0; B 3x16KB at 24576. Tri-buffered, staged 2 ahead.
// Superrow swizzle (128B = 2 rows): s=r>>1, slot=((r&1)<<2)|(k>>3);
// phys = s*128 + ((slot ^ (s&7))<<4) + (k&7)*2. Stage pre-swizzles global source.
template <int KIND>  // 0 shared-up, 1 routed-up, 2 shared-down splitK, 3 routed-down
__global__ __launch_bounds__(256, 2) void gemm8p(
    const unsigned short* __restrict__ A, const unsigned short* __restrict__ Ball,
    const int* __restrict__ cnt, const int* __restrict__ offs,
    const int* __restrict__ list, const float* __restrict__ cw,
    unsigned short* __restrict__ hout, float* __restrict__ fout,
    const int* __restrict__ table) {
    constexpr bool ROUTED = (KIND == 1 || KIND == 3);
    constexpr bool UP = (KIND <= 1);
    constexpr int K = (KIND <= 1) ? 2048 : 1024;
    constexpr int NT = K / 32;
    constexpr int ASTR = (KIND == 3) ? 1024 : 2048;
    constexpr int BSTR = (KIND == 3) ? 1024 : 2048;

    int bx, rb, e, M, obase;
    if constexpr (ROUTED) {
        int bid = blockIdx.x;
        int slot = bid >> 3;
        if (slot >= table[255]) return;
        bx = bid & 7;
        int pk = table[slot];
        e = pk >> 16;
        rb = pk & 0xFFFF;
        M = cnt[e];
        obase = offs[e];
    } else {
        bx = blockIdx.x; rb = blockIdx.y * 128; e = 0; M = T_TOK; obase = 0;
    }
    const int kb = (KIND == 2) ? blockIdx.z * 1024 : 0;
    const unsigned short* Bp = Ball +
        (KIND == 1 ? (size_t)e * 2048 * 2048 : KIND == 3 ? (size_t)e * 2048 * 1024 : 0);

    extern __shared__ char smem[];

    const int tid = threadIdx.x;
    const int lane = tid & 63;
    const int wn = tid >> 6;                 // 4 waves, wave tile 128x64 (wm=0)
    const int fr = lane & 15, fq = lane >> 4;
    const int offR = ((fr >> 1) << 7) + (((((fr & 1) << 2) | fq) ^ (fr >> 1)) << 4);
    const int d16 = tid * 16;

    // staging source maps (pre-swizzled global addresses)
    const unsigned short* pA[2];
    const unsigned short* pB[4];
#pragma unroll
    for (int i = 0; i < 2; ++i) {
        int c = i * 256 + tid, s = c >> 3, sl = (c & 7) ^ (s & 7);
        int rA = 2 * s + (sl >> 2), kk = (sl & 3) * 8;
        int gr = rb + rA;
        int cr = (gr < M) ? gr : (M - 1);
        size_t arow;
        if (KIND == 1)      arow = (size_t)list[e * T_TOK + cr];
        else if (KIND == 3) arow = (size_t)(obase + cr);
        else                arow = (size_t)gr;
        pA[i] = A + arow * ASTR + kb + kk;
    }
#pragma unroll
    for (int i = 0; i < 4; ++i) {
        int c = i * 256 + tid, s = c >> 3, sl = (c & 7) ^ (s & 7);
        int rB = 2 * s + (sl >> 2), kk = (sl & 3) * 8;
        pB[i] = Bp + (size_t)(bx * 256 + rB) * BSTR + kb + kk;
    }

    f32x4 acc[8][4];
#pragma unroll
    for (int m = 0; m < 8; ++m)
#pragma unroll
        for (int n = 0; n < 4; ++n) acc[m][n] = (f32x4)0.f;

    // prologue: stage tiles 0 and 1
#pragma unroll
    for (int i = 0; i < 2; ++i) gload16(pA[i], (void*)(smem + i * 4096 + d16));
#pragma unroll
    for (int i = 0; i < 4; ++i) gload16(pB[i], (void*)(smem + 24576 + i * 4096 + d16));
#pragma unroll
    for (int i = 0; i < 2; ++i) gload16(pA[i] + 32, (void*)(smem + 8192 + i * 4096 + d16));
#pragma unroll
    for (int i = 0; i < 4; ++i) gload16(pB[i] + 32, (void*)(smem + 24576 + 16384 + i * 4096 + d16));
#pragma unroll
    for (int i = 0; i < 2; ++i) pA[i] += 64;
#pragma unroll
    for (int i = 0; i < 4; ++i) pB[i] += 64;
    asm volatile("s_waitcnt vmcnt(6)" ::: "memory");
    __builtin_amdgcn_s_barrier();

    int bA = 0, bA2 = 16384;          // A bufs 0,8192,16384
    int bB = 0, bB2 = 32768;          // B bufs 0,16384,32768 (+24576)
    for (int t = 0; t < NT; ++t) {
        short8 aF[8], bF[4];
#pragma unroll
        for (int m = 0; m < 8; ++m)
            aF[m] = *(const short8*)(smem + bA + m * 1024 + offR);
#pragma unroll
        for (int n = 0; n < 4; ++n)
            bF[n] = *(const short8*)(smem + 24576 + bB + wn * 4096 + n * 1024 + offR);
        const bool more = (t + 2 < NT);
        if (more) {
#pragma unroll
            for (int i = 0; i < 2; ++i) gload16(pA[i], (void*)(smem + bA2 + i * 4096 + d16));
#pragma unroll
            for (int i = 0; i < 4; ++i) gload16(pB[i], (void*)(smem + 24576 + bB2 + i * 4096 + d16));
#pragma unroll
            for (int i = 0; i < 2; ++i) pA[i] += 32;
#pragma unroll
            for (int i = 0; i < 4; ++i) pB[i] += 32;
        }
        __builtin_amdgcn_s_setprio(1);
#pragma unroll
        for (int m = 0; m < 8; ++m)
#pragma unroll
            for (int n = 0; n < 4; ++n)
                acc[m][n] = __builtin_amdgcn_mfma_f32_16x16x32_bf16(aF[m], bF[n], acc[m][n], 0, 0, 0);
        __builtin_amdgcn_s_setprio(0);
        if (more) { asm volatile("s_waitcnt vmcnt(6)" ::: "memory"); }
        else      { asm volatile("s_waitcnt vmcnt(0)" ::: "memory"); }
        __builtin_amdgcn_s_barrier();
        bA = (bA == 16384) ? 0 : bA + 8192;
        bA2 = (bA2 == 16384) ? 0 : bA2 + 8192;
        bB = (bB == 32768) ? 0 : bB + 16384;
        bB2 = (bB2 == 32768) ? 0 : bB2 + 16384;
    }

    // epilogue
    if constexpr (UP) {
        constexpr int LDO = (KIND == 1) ? NI : NSH;
#pragma unroll
        for (int m = 0; m < 8; ++m)
#pragma unroll
            for (int q = 0; q < 4; ++q) {
                int gr = rb + m * 16 + fq * 4 + q;
                if (gr < M) {
                    float coef = 1.f;
                    if constexpr (KIND == 1) coef = cw[e * T_TOK + gr];
                    size_t orow = (size_t)(obase + gr) * LDO;
#pragma unroll
                    for (int nfp = 0; nfp < 2; ++nfp) {
                        float c1 = acc[m][2 * nfp][q], c3 = acc[m][2 * nfp + 1][q];
                        float h = c1 / (1.f + __expf(-c1)) * c3 * coef;
                        int ncol = (bx * 8 + wn * 2 + nfp) * 16 + fr;
                        hout[orow + ncol] = f2bf(h);
                    }
                }
            }
    } else {
#pragma unroll
        for (int m = 0; m < 8; ++m)
#pragma unroll
            for (int q = 0; q < 4; ++q) {
                int gr = rb + m * 16 + fq * 4 + q;
                if (gr < M) {
                    int orow = (KIND == 3) ? list[e * T_TOK + gr] : gr;
#pragma unroll
                    for (int nf = 0; nf < 4; ++nf) {
                        int col = bx * 256 + wn * 64 + nf * 16 + fr;
                        atomicAdd(fout + (size_t)orow * DIMD + col, acc[m][nf][q]);
                    }
                }
            }
    }
}

extern "C" void kernel_launch(void* const* d_in, const int* in_sizes, int n_in,
                              void* d_out, int out_size, void* d_ws, size_t ws_size,
                              hipStream_t stream) {
    const float* x   = (const float*)d_in[0];
    const float* gw  = (const float*)d_in[1];
    const float* w1  = (const float*)d_in[2];
    const float* w2  = (const float*)d_in[3];
    const float* w3  = (const float*)d_in[4];
    const float* ws1 = (const float*)d_in[5];
    const float* ws2 = (const float*)d_in[6];
    const float* ws3 = (const float*)d_in[7];
    float* out = (float*)d_out;

    char* p = (char*)d_ws;
    unsigned short* xb   = (unsigned short*)p; p += (size_t)T_TOK * DIMD * 2;
    unsigned short* hs   = (unsigned short*)p; p += (size_t)T_TOK * NSH * 2;
    unsigned short* hbuf = (unsigned short*)p; p += (size_t)T_TOK * TOPK * NI * 2;
    unsigned short* upT  = (unsigned short*)p; p += (size_t)NEXP * 2048 * DIMD * 2;
    unsigned short* w2T  = (unsigned short*)p; p += (size_t)NEXP * DIMD * NI * 2;
    unsigned short* upsT = (unsigned short*)p; p += (size_t)2 * NSH * DIMD * 2;
    unsigned short* ws2T = (unsigned short*)p; p += (size_t)DIMD * NSH * 2;
    float* gwT = (float*)p;                    p += (size_t)NEXP * DIMD * 4;
    float* cw = (float*)p;                     p += (size_t)NEXP * T_TOK * 4;
    int* list = (int*)p;                       p += (size_t)NEXP * T_TOK * 4;
    int* tk_er = (int*)p;                      p += (size_t)T_TOK * TOPK * 4;
    float* tk_wv = (float*)p;                  p += (size_t)T_TOK * TOPK * 4;
    int* blk_cnt = (int*)p;                    p += (size_t)1024 * 16 * 4;
    int* blk_off = (int*)p;                    p += (size_t)1024 * 16 * 4;
    int* cnt = (int*)p;                        p += 256;
    int* offs = (int*)p;                       p += 256;
    int* table = (int*)p;                      p += 1024;
    if ((size_t)(p - (char*)d_ws) > ws_size) return;

    hipFuncSetAttribute((const void*)&gemm8p<0>, hipFuncAttributeMaxDynamicSharedMemorySize, 73728);
    hipFuncSetAttribute((const void*)&gemm8p<1>, hipFuncAttributeMaxDynamicSharedMemorySize, 73728);
    hipFuncSetAttribute((const void*)&gemm8p<2>, hipFuncAttributeMaxDynamicSharedMemorySize, 73728);
    hipFuncSetAttribute((const void*)&gemm8p<3>, hipFuncAttributeMaxDynamicSharedMemorySize, 73728);

    hipMemsetAsync(out, 0, (size_t)out_size * 4, stream);
    gwt_kernel<<<(NEXP * DIMD) / 256, 256, 0, stream>>>(gw, gwT);
    gate_kernel<<<T_TOK / 4, 256, 0, stream>>>(x, gwT, blk_cnt, tk_er, tk_wv);
    scan_kernel<<<1, 256, 0, stream>>>(blk_cnt, blk_off, cnt, offs, table);
    fill_kernel<<<T_TOK * TOPK / 256, 256, 0, stream>>>(tk_er, tk_wv, blk_off, list, cw);
    cvt_kernel<<<(T_TOK * DIMD / 8) / 256, 256, 0, stream>>>(x, xb);

    tq_kernel<1><<<dim3(NI / 32, DIMD / 32, NEXP), 256, 0, stream>>>(w1, upT, DIMD, NI, (size_t)2048 * DIMD);
    tq_kernel<2><<<dim3(NI / 32, DIMD / 32, NEXP), 256, 0, stream>>>(w3, upT, DIMD, NI, (size_t)2048 * DIMD);
    tq_kernel<1><<<dim3(NSH / 32, DIMD / 32, 1), 256, 0, stream>>>(ws1, upsT, DIMD, NSH, 0);
    tq_kernel<2><<<dim3(NSH / 32, DIMD / 32, 1), 256, 0, stream>>>(ws3, upsT, DIMD, NSH, 0);
    tq_kernel<0><<<dim3(DIMD / 32, NI / 32, NEXP), 256, 0, stream>>>(w2, w2T, NI, DIMD, (size_t)DIMD * NI);
    tq_kernel<0><<<dim3(DIMD / 32, NSH / 32, 1), 256, 0, stream>>>(ws2, ws2T, NSH, DIMD, 0);

    // shared-up: 16 N-tiles x 32 M-tiles = 512 blocks (one resident round)
    gemm8p<0><<<dim3(16, 32, 1), 256, 73728, stream>>>(
        xb, upsT, nullptr, nullptr, nullptr, nullptr, hs, nullptr, nullptr);
    // shared-down: 8 x 32 x splitK2 = 512 blocks
    gemm8p<2><<<dim3(8, 32, 2), 256, 73728, stream>>>(
        hs, ws2T, nullptr, nullptr, nullptr, nullptr, nullptr, out, nullptr);
    // routed: slots(BM=128) x 8 N-tiles
    gemm8p<1><<<1152, 256, 73728, stream>>>(
        xb, upT, cnt, offs, list, cw, hbuf, nullptr, table);
    gemm8p<3><<<1152, 256, 73728, stream>>>(
        hbuf, w2T, cnt, offs, list, nullptr, nullptr, out, table);
}

// Round 11
// 663.880 us; speedup vs baseline: 1.0829x; 1.0829x over previous
//
#include <hip/hip_runtime.h>
#include <hip/hip_bf16.h>
#include <stdint.h>

#define T_TOK 4096
#define DIMD  2048
#define NEXP  16
#define TOPK  4
#define NI    1024
#define NSH   2048

typedef __attribute__((ext_vector_type(8))) short short8;
typedef __attribute__((ext_vector_type(4))) float f32x4;
typedef __attribute__((ext_vector_type(4))) unsigned short u16x4;
typedef __attribute__((ext_vector_type(8))) unsigned short u16x8;

__device__ __forceinline__ unsigned short f2bf(float f) {
    union { float f; unsigned u; } v; v.f = f;
    return (unsigned short)((v.u + 0x7fffu + ((v.u >> 16) & 1u)) >> 16);
}

__device__ __forceinline__ void gload16(const void* g, void* l) {
    __builtin_amdgcn_global_load_lds(
        (const __attribute__((address_space(1))) void*)g,
        (__attribute__((address_space(3))) void*)l, 16, 0, 0);
}

// ---------------- gw transpose ----------------
__global__ __launch_bounds__(256) void gwt_kernel(const float* __restrict__ gw,
                                                  float* __restrict__ gwT) {
    int i = blockIdx.x * 256 + threadIdx.x;
    int d = i >> 4, e = i & 15;
    gwT[e * DIMD + d] = gw[i];
}

// ---------------- gate: scores + top-4, LDS-histogram routing ----------------
__global__ __launch_bounds__(256) void gate_kernel(const float* __restrict__ x,
                                                   const float* __restrict__ gwT,
                                                   int* __restrict__ blk_cnt,
                                                   int* __restrict__ tk_er,
                                                   float* __restrict__ tk_wv) {
    __shared__ int h[16];
    const int blk = blockIdx.x;
    const int t = blk * 4 + (threadIdx.x >> 6);
    const int lane = threadIdx.x & 63;
    if (threadIdx.x < 16) h[threadIdx.x] = 0;
    __syncthreads();

    const f32x4* xr = (const f32x4*)(x + (size_t)t * DIMD);
    f32x4 xv[8];
#pragma unroll
    for (int i = 0; i < 8; ++i) xv[i] = xr[i * 64 + lane];

    float acc[NEXP];
#pragma unroll
    for (int e = 0; e < NEXP; ++e) {
        const f32x4* gr = (const f32x4*)(gwT + e * DIMD);
        float s = 0.f;
#pragma unroll
        for (int i = 0; i < 8; ++i) {
            f32x4 gv = gr[i * 64 + lane];
            s += xv[i][0] * gv[0] + xv[i][1] * gv[1] +
                 xv[i][2] * gv[2] + xv[i][3] * gv[3];
        }
        acc[e] = s;
    }
#pragma unroll
    for (int e = 0; e < NEXP; ++e) {
        float v = acc[e];
#pragma unroll
        for (int off = 32; off; off >>= 1) v += __shfl_xor(v, off, 64);
        acc[e] = v;
    }
    float m = acc[0];
#pragma unroll
    for (int e = 1; e < NEXP; ++e) m = fmaxf(m, acc[e]);
    float s = 0.f;
#pragma unroll
    for (int e = 0; e < NEXP; ++e) { acc[e] = expf(acc[e] - m); s += acc[e]; }
    float inv = 1.f / s;
#pragma unroll
    for (int e = 0; e < NEXP; ++e) acc[e] *= inv;

    float w4[TOPK]; int i4[TOPK];
#pragma unroll
    for (int k = 0; k < TOPK; ++k) {
        float bv = -1.f; int be = 0;
#pragma unroll
        for (int e = 0; e < NEXP; ++e)
            if (acc[e] > bv) { bv = acc[e]; be = e; }
        w4[k] = bv; i4[k] = be;
#pragma unroll
        for (int e = 0; e < NEXP; ++e)
            if (e == be) acc[e] = -1.f;
    }

    if (lane == 0) {
        int r4[TOPK];
#pragma unroll
        for (int k = 0; k < TOPK; ++k) r4[k] = atomicAdd(&h[i4[k]], 1);
#pragma unroll
        for (int k = 0; k < TOPK; ++k) {
            tk_er[t * 4 + k] = (i4[k] << 20) | r4[k];
            tk_wv[t * 4 + k] = w4[k];
        }
    }
    __syncthreads();
    if (threadIdx.x < 16) blk_cnt[blk * 16 + threadIdx.x] = h[threadIdx.x];
}

// ---------------- hierarchical scan; slot table at BM=128 ----------------
__global__ __launch_bounds__(256) void scan_kernel(const int* __restrict__ blk_cnt,
                                                   int* __restrict__ blk_off,
                                                   int* __restrict__ cnt,
                                                   int* __restrict__ offs,
                                                   int* __restrict__ table) {
    __shared__ int gsum[16][17];
    __shared__ int gbase[16][17];
    __shared__ int csh[16];
    int tid = threadIdx.x;
    int e = tid >> 4, g = tid & 15;
    {
        int s = 0;
        for (int b = g * 64; b < g * 64 + 64; ++b) s += blk_cnt[b * 16 + e];
        gsum[e][g] = s;
    }
    __syncthreads();
    if (tid < 16) {
        int run = 0;
        for (int g2 = 0; g2 < 16; ++g2) { gbase[tid][g2] = run; run += gsum[tid][g2]; }
        csh[tid] = run;
        cnt[tid] = run;
    }
    __syncthreads();
    {
        int run = gbase[e][g];
        for (int b = g * 64; b < g * 64 + 64; ++b) {
            blk_off[b * 16 + e] = run;
            run += blk_cnt[b * 16 + e];
        }
    }
    if (tid == 0) {
        int o = 0;
        for (int e2 = 0; e2 < 16; ++e2) { offs[e2] = o; o += csh[e2]; }
        offs[NEXP] = o;
        int ns = 0;
        for (int e2 = 0; e2 < 16; ++e2)
            for (int rb = 0; rb < csh[e2]; rb += 128) {
                table[ns] = (e2 << 16) | rb; ++ns;
            }
        table[255] = ns;
    }
}

// ---------------- fill compacted expert lists ----------------
__global__ __launch_bounds__(256) void fill_kernel(const int* __restrict__ tk_er,
                                                   const float* __restrict__ tk_wv,
                                                   const int* __restrict__ blk_off,
                                                   int* __restrict__ list,
                                                   float* __restrict__ cw) {
    int i = blockIdx.x * 256 + threadIdx.x;
    int rec = tk_er[i];
    int e = rec >> 20, r = rec & 0xFFFFF;
    int t = i >> 2;
    int ro = blk_off[(t >> 2) * 16 + e] + r;
    list[e * T_TOK + ro] = t;
    cw[e * T_TOK + ro] = tk_wv[i];
}

// ---------------- x fp32 -> bf16 ----------------
__global__ __launch_bounds__(256) void cvt_kernel(const float* __restrict__ x,
                                                  unsigned short* __restrict__ xb) {
    int i = blockIdx.x * 256 + threadIdx.x;
    const f32x4* src = (const f32x4*)x;
    f32x4 a = src[i * 2 + 0];
    f32x4 b = src[i * 2 + 1];
    short8 o;
#pragma unroll
    for (int j = 0; j < 4; ++j) o[j] = (short)f2bf(a[j]);
#pragma unroll
    for (int j = 0; j < 4; ++j) o[4 + j] = (short)f2bf(b[j]);
    ((short8*)xb)[i] = o;
}

// ---------------- weight transpose+convert: 64x64 tiles, 16B stores ----------------
// pair: w1,w3 -> interleaved rows (n>>4)*32 + half*16 + (n&15)
__global__ __launch_bounds__(256) void tq_pair(const float* __restrict__ s1,
                                               const float* __restrict__ s3,
                                               unsigned short* __restrict__ dst,
                                               int K, int N,
                                               size_t srcStrideE, size_t dstStrideE) {
    int e = blockIdx.z;
    s1 += (size_t)e * srcStrideE;
    s3 += (size_t)e * srcStrideE;
    dst += (size_t)e * dstStrideE;
    __shared__ unsigned short tile[64][72];
    const int t = threadIdx.x;
    const int k0 = blockIdx.y * 64, n0 = blockIdx.x * 64;
    const int lr = t >> 4, lc4 = (t & 15) * 4;
    const int sr8 = (t & 7) * 8, sn = t >> 3;
#pragma unroll
    for (int half = 0; half < 2; ++half) {
        const float* src = half ? s3 : s1;
#pragma unroll
        for (int r = 0; r < 4; ++r) {
            f32x4 v = *(const f32x4*)(src + (size_t)(k0 + lr + r * 16) * N + n0 + lc4);
#pragma unroll
            for (int j = 0; j < 4; ++j) tile[lr + r * 16][lc4 + j] = f2bf(v[j]);
        }
        __syncthreads();
#pragma unroll
        for (int q = 0; q < 2; ++q) {
            int nn = sn + q * 32;
            int n = n0 + nn;
            int rrow = (n >> 4) * 32 + half * 16 + (n & 15);
            u16x8 o;
#pragma unroll
            for (int j = 0; j < 8; ++j) o[j] = tile[sr8 + j][nn];
            *(u16x8*)(dst + (size_t)rrow * K + k0 + sr8) = o;
        }
        __syncthreads();
    }
}

// plain: src [K][N] -> dst [N][K]
__global__ __launch_bounds__(256) void tq_plain(const float* __restrict__ src,
                                                unsigned short* __restrict__ dst,
                                                int K, int N,
                                                size_t srcStrideE, size_t dstStrideE) {
    int e = blockIdx.z;
    src += (size_t)e * srcStrideE;
    dst += (size_t)e * dstStrideE;
    __shared__ unsigned short tile[64][72];
    const int t = threadIdx.x;
    const int k0 = blockIdx.y * 64, n0 = blockIdx.x * 64;
    const int lr = t >> 4, lc4 = (t & 15) * 4;
    const int sr8 = (t & 7) * 8, sn = t >> 3;
#pragma unroll
    for (int r = 0; r < 4; ++r) {
        f32x4 v = *(const f32x4*)(src + (size_t)(k0 + lr + r * 16) * N + n0 + lc4);
#pragma unroll
        for (int j = 0; j < 4; ++j) tile[lr + r * 16][lc4 + j] = f2bf(v[j]);
    }
    __syncthreads();
#pragma unroll
    for (int q = 0; q < 2; ++q) {
        int nn = sn + q * 32;
        int n = n0 + nn;
        u16x8 o;
#pragma unroll
        for (int j = 0; j < 8; ++j) o[j] = tile[sr8 + j][nn];
        *(u16x8*)(dst + (size_t)n * K + k0 + sr8) = o;
    }
}

// ======== fused 128x256 GEMM (R9 core): shared blocks [0,512) + routed ========
// 8 waves (wave tile 64x64), BK=32, LDS 72KB: A 3x8KB @0, B 3x16KB @24576.
// Tri-buffered, staged 2 ahead, vmcnt(6), 1 barrier/K-tile.
// Superrow swizzle: s=r>>1, slot=((r&1)<<2)|(k>>3); phys = s*128+((slot^(s&7))<<4)+(k&7)*2.
template <bool UP>  // UP: K=2048 (xb -> hs/hbuf); !UP: K=1024/tile (hs/hbuf -> out)
__global__ __launch_bounds__(512, 2) void gemm_f(
    const unsigned short* __restrict__ Ash, const unsigned short* __restrict__ Art,
    const unsigned short* __restrict__ Bsh, const unsigned short* __restrict__ Brt,
    const int* __restrict__ cnt, const int* __restrict__ offs,
    const int* __restrict__ list, const float* __restrict__ cw,
    unsigned short* __restrict__ hs, unsigned short* __restrict__ hbuf,
    float* __restrict__ fout, const int* __restrict__ table) {
    constexpr int NT = UP ? 64 : 32;

    const int bid = blockIdx.x;
    const bool routed = bid >= 512;
    int bx, rb, e = 0, M, obase = 0, kb = 0;
    const unsigned short* Ap;
    const unsigned short* Bp;
    int ASTRr, BSTRr;
    if (!routed) {
        if (UP) { bx = bid & 15; rb = (bid >> 4) * 128; }
        else    { bx = bid & 7;  rb = ((bid >> 3) & 31) * 128; kb = (bid >> 8) * 1024; }
        M = T_TOK;
        Ap = Ash; Bp = Bsh;
        ASTRr = 2048; BSTRr = 2048;
    } else {
        int rbid = bid - 512;
        int slot = rbid >> 3;
        if (slot >= table[255]) return;
        bx = rbid & 7;
        int pk = table[slot];
        e = pk >> 16; rb = pk & 0xFFFF;
        M = cnt[e]; obase = offs[e];
        Ap = Art;
        Bp = Brt + (UP ? (size_t)e * 2048 * 2048 : (size_t)e * 2048 * 1024);
        ASTRr = UP ? 2048 : 1024;
        BSTRr = UP ? 2048 : 1024;
    }

    extern __shared__ char smem[];

    const int tid = threadIdx.x;
    const int lane = tid & 63, wid = tid >> 6;
    const int wm = wid >> 2, wn = wid & 3;          // wave tile 64x64
    const int fr = lane & 15, fq = lane >> 4;
    const int offR = ((fr >> 1) << 7) + (((((fr & 1) << 2) | fq) ^ (fr >> 1)) << 4);
    const int d16 = tid * 16;

    // staging source maps (pre-swizzled global addresses)
    const unsigned short* pA;
    const unsigned short* pB0;
    const unsigned short* pB1;
    {
        int c = tid, s = c >> 3, sl = (c & 7) ^ (s & 7);
        int rA = 2 * s + (sl >> 2), kk = (sl & 3) * 8;
        int gr = rb + rA;
        int cr = (gr < M) ? gr : (M - 1);
        size_t arow;
        if (!routed)  arow = (size_t)gr;
        else if (UP)  arow = (size_t)list[e * T_TOK + cr];
        else          arow = (size_t)(obase + cr);
        pA = Ap + arow * ASTRr + kb + kk;
    }
#pragma unroll
    for (int u = 0; u < 2; ++u) {
        int c = u * 512 + tid, s = c >> 3, sl = (c & 7) ^ (s & 7);
        int rB = 2 * s + (sl >> 2), kk = (sl & 3) * 8;
        const unsigned short* p = Bp + (size_t)(bx * 256 + rB) * BSTRr + kb + kk;
        if (u == 0) pB0 = p; else pB1 = p;
    }

    f32x4 acc[4][4];
#pragma unroll
    for (int m = 0; m < 4; ++m)
#pragma unroll
        for (int n = 0; n < 4; ++n) acc[m][n] = (f32x4)0.f;

    // prologue: stage tiles 0,1
    gload16(pA,      (void*)(smem + 0 + d16));
    gload16(pA + 32, (void*)(smem + 8192 + d16));
    gload16(pB0,      (void*)(smem + 24576 + d16));
    gload16(pB1,      (void*)(smem + 24576 + 8192 + d16));
    gload16(pB0 + 32, (void*)(smem + 24576 + 16384 + d16));
    gload16(pB1 + 32, (void*)(smem + 24576 + 16384 + 8192 + d16));
    pA += 64; pB0 += 64; pB1 += 64;
    asm volatile("s_waitcnt vmcnt(0)" ::: "memory");
    __builtin_amdgcn_s_barrier();

    int bA = 0, bA2 = 16384;          // A bufs 0,8192,16384
    int bB = 0, bB2 = 32768;          // B bufs 0,16384,32768 (+24576)
    for (int t = 0; t < NT; ++t) {
        short8 aF[4], bF[4];
#pragma unroll
        for (int m = 0; m < 4; ++m)
            aF[m] = *(const short8*)(smem + bA + wm * 4096 + m * 1024 + offR);
#pragma unroll
        for (int n = 0; n < 4; ++n)
            bF[n] = *(const short8*)(smem + 24576 + bB + wn * 4096 + n * 1024 + offR);
        const bool more = (t + 2 < NT);
        if (more) {
            gload16(pA, (void*)(smem + bA2 + d16));
            gload16(pB0, (void*)(smem + 24576 + bB2 + d16));
            gload16(pB1, (void*)(smem + 24576 + bB2 + 8192 + d16));
            pA += 32; pB0 += 32; pB1 += 32;
        }
        __builtin_amdgcn_s_setprio(1);
#pragma unroll
        for (int m = 0; m < 4; ++m)
#pragma unroll
            for (int n = 0; n < 4; ++n)
                acc[m][n] = __builtin_amdgcn_mfma_f32_16x16x32_bf16(aF[m], bF[n], acc[m][n], 0, 0, 0);
        __builtin_amdgcn_s_setprio(0);
        if (more) { asm volatile("s_waitcnt vmcnt(3)" ::: "memory"); }
        else      { asm volatile("s_waitcnt vmcnt(0)" ::: "memory"); }
        __builtin_amdgcn_s_barrier();
        bA = (bA == 16384) ? 0 : bA + 8192;
        bA2 = (bA2 == 16384) ? 0 : bA2 + 8192;
        bB = (bB == 32768) ? 0 : bB + 16384;
        bB2 = (bB2 == 32768) ? 0 : bB2 + 16384;
    }

    // epilogue
    if constexpr (UP) {
        const int LDO = routed ? NI : NSH;
        unsigned short* hp = routed ? hbuf : hs;
#pragma unroll
        for (int m = 0; m < 4; ++m)
#pragma unroll
            for (int q = 0; q < 4; ++q) {
                int gr = rb + wm * 64 + m * 16 + fq * 4 + q;
                if (gr < M) {
                    float coef = routed ? cw[e * T_TOK + gr] : 1.f;
                    size_t orow = (size_t)((routed ? obase : 0) + gr) * LDO;
#pragma unroll
                    for (int nfp = 0; nfp < 2; ++nfp) {
                        float c1 = acc[m][2 * nfp][q], c3 = acc[m][2 * nfp + 1][q];
                        float h = c1 / (1.f + __expf(-c1)) * c3 * coef;
                        int ncol = (bx * 8 + wn * 2 + nfp) * 16 + fr;
                        hp[orow + ncol] = f2bf(h);
                    }
                }
            }
    } else {
#pragma unroll
        for (int m = 0; m < 4; ++m)
#pragma unroll
            for (int q = 0; q < 4; ++q) {
                int gr = rb + wm * 64 + m * 16 + fq * 4 + q;
                if (gr < M) {
                    int orow = routed ? list[e * T_TOK + gr] : gr;
#pragma unroll
                    for (int nf = 0; nf < 4; ++nf) {
                        int col = bx * 256 + wn * 64 + nf * 16 + fr;
                        atomicAdd(fout + (size_t)orow * DIMD + col, acc[m][nf][q]);
                    }
                }
            }
    }
}

extern "C" void kernel_launch(void* const* d_in, const int* in_sizes, int n_in,
                              void* d_out, int out_size, void* d_ws, size_t ws_size,
                              hipStream_t stream) {
    const float* x   = (const float*)d_in[0];
    const float* gw  = (const float*)d_in[1];
    const float* w1  = (const float*)d_in[2];
    const float* w2  = (const float*)d_in[3];
    const float* w3  = (const float*)d_in[4];
    const float* ws1 = (const float*)d_in[5];
    const float* ws2 = (const float*)d_in[6];
    const float* ws3 = (const float*)d_in[7];
    float* out = (float*)d_out;

    char* p = (char*)d_ws;
    unsigned short* xb   = (unsigned short*)p; p += (size_t)T_TOK * DIMD * 2;
    unsigned short* hs   = (unsigned short*)p; p += (size_t)T_TOK * NSH * 2;
    unsigned short* hbuf = (unsigned short*)p; p += (size_t)T_TOK * TOPK * NI * 2;
    unsigned short* upT  = (unsigned short*)p; p += (size_t)NEXP * 2048 * DIMD * 2;
    unsigned short* w2T  = (unsigned short*)p; p += (size_t)NEXP * DIMD * NI * 2;
    unsigned short* upsT = (unsigned short*)p; p += (size_t)2 * NSH * DIMD * 2;
    unsigned short* ws2T = (unsigned short*)p; p += (size_t)DIMD * NSH * 2;
    float* gwT = (float*)p;                    p += (size_t)NEXP * DIMD * 4;
    float* cw = (float*)p;                     p += (size_t)NEXP * T_TOK * 4;
    int* list = (int*)p;                       p += (size_t)NEXP * T_TOK * 4;
    int* tk_er = (int*)p;                      p += (size_t)T_TOK * TOPK * 4;
    float* tk_wv = (float*)p;                  p += (size_t)T_TOK * TOPK * 4;
    int* blk_cnt = (int*)p;                    p += (size_t)1024 * 16 * 4;
    int* blk_off = (int*)p;                    p += (size_t)1024 * 16 * 4;
    int* cnt = (int*)p;                        p += 256;
    int* offs = (int*)p;                       p += 256;
    int* table = (int*)p;                      p += 1024;
    if ((size_t)(p - (char*)d_ws) > ws_size) return;

    hipFuncSetAttribute((const void*)&gemm_f<true>, hipFuncAttributeMaxDynamicSharedMemorySize, 73728);
    hipFuncSetAttribute((const void*)&gemm_f<false>, hipFuncAttributeMaxDynamicSharedMemorySize, 73728);

    hipMemsetAsync(out, 0, (size_t)out_size * 4, stream);
    gwt_kernel<<<(NEXP * DIMD) / 256, 256, 0, stream>>>(gw, gwT);
    gate_kernel<<<T_TOK / 4, 256, 0, stream>>>(x, gwT, blk_cnt, tk_er, tk_wv);
    scan_kernel<<<1, 256, 0, stream>>>(blk_cnt, blk_off, cnt, offs, table);
    fill_kernel<<<T_TOK * TOPK / 256, 256, 0, stream>>>(tk_er, tk_wv, blk_off, list, cw);
    cvt_kernel<<<(T_TOK * DIMD / 8) / 256, 256, 0, stream>>>(x, xb);

    // weight pre-pass: 64x64 tiles, paired w1/w3
    tq_pair<<<dim3(NI / 64, DIMD / 64, NEXP), 256, 0, stream>>>(
        w1, w3, upT, DIMD, NI, (size_t)DIMD * NI, (size_t)2048 * DIMD);
    tq_pair<<<dim3(NSH / 64, DIMD / 64, 1), 256, 0, stream>>>(
        ws1, ws3, upsT, DIMD, NSH, 0, 0);
    tq_plain<<<dim3(DIMD / 64, NI / 64, NEXP), 256, 0, stream>>>(
        w2, w2T, NI, DIMD, (size_t)NI * DIMD, (size_t)DIMD * NI);
    tq_plain<<<dim3(DIMD / 64, NSH / 64, 1), 256, 0, stream>>>(
        ws2, ws2T, NSH, DIMD, 0, 0);

    // fused up: [0,512) shared (16 bx x 32 rb), [512,...) routed slots x 8
    gemm_f<true><<<512 + 144 * 8, 512, 73728, stream>>>(
        xb, xb, upsT, upT, cnt, offs, list, cw, hs, hbuf, nullptr, table);
    // fused down: [0,512) shared (8 bx x 32 rb x 2 splitK), [512,...) routed
    gemm_f<false><<<512 + 144 * 8, 512, 73728, stream>>>(
        hs, hbuf, ws2T, w2T, cnt, offs, list, nullptr, nullptr, nullptr, out, table);
}

// Round 12
// 627.532 us; speedup vs baseline: 1.1457x; 1.0579x over previous
//
#include <hip/hip_runtime.h>
#include <hip/hip_bf16.h>
#include <stdint.h>

#define T_TOK 4096
#define DIMD  2048
#define NEXP  16
#define TOPK  4
#define NI    1024
#define NSH   2048

typedef __attribute__((ext_vector_type(8))) short short8;
typedef __attribute__((ext_vector_type(4))) float f32x4;
typedef __attribute__((ext_vector_type(4))) unsigned short u16x4;
typedef __attribute__((ext_vector_type(8))) unsigned short u16x8;

__device__ __forceinline__ unsigned short f2bf(float f) {
    union { float f; unsigned u; } v; v.f = f;
    return (unsigned short)((v.u + 0x7fffu + ((v.u >> 16) & 1u)) >> 16);
}

__device__ __forceinline__ void gload16(const void* g, void* l) {
    __builtin_amdgcn_global_load_lds(
        (const __attribute__((address_space(1))) void*)g,
        (__attribute__((address_space(3))) void*)l, 16, 0, 0);
}

// ---------------- gw transpose ----------------
__global__ __launch_bounds__(256) void gwt_kernel(const float* __restrict__ gw,
                                                  float* __restrict__ gwT) {
    int i = blockIdx.x * 256 + threadIdx.x;
    int d = i >> 4, e = i & 15;
    gwT[e * DIMD + d] = gw[i];
}

// ---------------- gate: scores + top-4, LDS-histogram routing ----------------
__global__ __launch_bounds__(256) void gate_kernel(const float* __restrict__ x,
                                                   const float* __restrict__ gwT,
                                                   int* __restrict__ blk_cnt,
                                                   int* __restrict__ tk_er,
                                                   float* __restrict__ tk_wv) {
    __shared__ int h[16];
    const int blk = blockIdx.x;
    const int t = blk * 4 + (threadIdx.x >> 6);
    const int lane = threadIdx.x & 63;
    if (threadIdx.x < 16) h[threadIdx.x] = 0;
    __syncthreads();

    const f32x4* xr = (const f32x4*)(x + (size_t)t * DIMD);
    f32x4 xv[8];
#pragma unroll
    for (int i = 0; i < 8; ++i) xv[i] = xr[i * 64 + lane];

    float acc[NEXP];
#pragma unroll
    for (int e = 0; e < NEXP; ++e) {
        const f32x4* gr = (const f32x4*)(gwT + e * DIMD);
        float s = 0.f;
#pragma unroll
        for (int i = 0; i < 8; ++i) {
            f32x4 gv = gr[i * 64 + lane];
            s += xv[i][0] * gv[0] + xv[i][1] * gv[1] +
                 xv[i][2] * gv[2] + xv[i][3] * gv[3];
        }
        acc[e] = s;
    }
#pragma unroll
    for (int e = 0; e < NEXP; ++e) {
        float v = acc[e];
#pragma unroll
        for (int off = 32; off; off >>= 1) v += __shfl_xor(v, off, 64);
        acc[e] = v;
    }
    float m = acc[0];
#pragma unroll
    for (int e = 1; e < NEXP; ++e) m = fmaxf(m, acc[e]);
    float s = 0.f;
#pragma unroll
    for (int e = 0; e < NEXP; ++e) { acc[e] = expf(acc[e] - m); s += acc[e]; }
    float inv = 1.f / s;
#pragma unroll
    for (int e = 0; e < NEXP; ++e) acc[e] *= inv;

    float w4[TOPK]; int i4[TOPK];
#pragma unroll
    for (int k = 0; k < TOPK; ++k) {
        float bv = -1.f; int be = 0;
#pragma unroll
        for (int e = 0; e < NEXP; ++e)
            if (acc[e] > bv) { bv = acc[e]; be = e; }
        w4[k] = bv; i4[k] = be;
#pragma unroll
        for (int e = 0; e < NEXP; ++e)
            if (e == be) acc[e] = -1.f;
    }

    if (lane == 0) {
        int r4[TOPK];
#pragma unroll
        for (int k = 0; k < TOPK; ++k) r4[k] = atomicAdd(&h[i4[k]], 1);
#pragma unroll
        for (int k = 0; k < TOPK; ++k) {
            tk_er[t * 4 + k] = (i4[k] << 20) | r4[k];
            tk_wv[t * 4 + k] = w4[k];
        }
    }
    __syncthreads();
    if (threadIdx.x < 16) blk_cnt[blk * 16 + threadIdx.x] = h[threadIdx.x];
}

// ---------------- hierarchical scan; slot table at BM=128 ----------------
__global__ __launch_bounds__(256) void scan_kernel(const int* __restrict__ blk_cnt,
                                                   int* __restrict__ blk_off,
                                                   int* __restrict__ cnt,
                                                   int* __restrict__ offs,
                                                   int* __restrict__ table) {
    __shared__ int gsum[16][17];
    __shared__ int gbase[16][17];
    __shared__ int csh[16];
    int tid = threadIdx.x;
    int e = tid >> 4, g = tid & 15;
    {
        int s = 0;
        for (int b = g * 64; b < g * 64 + 64; ++b) s += blk_cnt[b * 16 + e];
        gsum[e][g] = s;
    }
    __syncthreads();
    if (tid < 16) {
        int run = 0;
        for (int g2 = 0; g2 < 16; ++g2) { gbase[tid][g2] = run; run += gsum[tid][g2]; }
        csh[tid] = run;
        cnt[tid] = run;
    }
    __syncthreads();
    {
        int run = gbase[e][g];
        for (int b = g * 64; b < g * 64 + 64; ++b) {
            blk_off[b * 16 + e] = run;
            run += blk_cnt[b * 16 + e];
        }
    }
    if (tid == 0) {
        int o = 0;
        for (int e2 = 0; e2 < 16; ++e2) { offs[e2] = o; o += csh[e2]; }
        offs[NEXP] = o;
        int ns = 0;
        for (int e2 = 0; e2 < 16; ++e2)
            for (int rb = 0; rb < csh[e2]; rb += 128) {
                table[ns] = (e2 << 16) | rb; ++ns;
            }
        table[255] = ns;
    }
}

// ---------------- fill compacted expert lists + token->row table ----------------
__global__ __launch_bounds__(256) void fill_kernel(const int* __restrict__ tk_er,
                                                   const float* __restrict__ tk_wv,
                                                   const int* __restrict__ blk_off,
                                                   const int* __restrict__ offs,
                                                   int* __restrict__ list,
                                                   float* __restrict__ cw,
                                                   int* __restrict__ rows) {
    int i = blockIdx.x * 256 + threadIdx.x;
    int rec = tk_er[i];
    int e = rec >> 20, r = rec & 0xFFFFF;
    int t = i >> 2;
    int ro = blk_off[(t >> 2) * 16 + e] + r;
    list[e * T_TOK + ro] = t;
    cw[e * T_TOK + ro] = tk_wv[i];
    rows[i] = offs[e] + ro;
}

// ---------------- x fp32 -> bf16 ----------------
__global__ __launch_bounds__(256) void cvt_kernel(const float* __restrict__ x,
                                                  unsigned short* __restrict__ xb) {
    int i = blockIdx.x * 256 + threadIdx.x;
    const f32x4* src = (const f32x4*)x;
    f32x4 a = src[i * 2 + 0];
    f32x4 b = src[i * 2 + 1];
    short8 o;
#pragma unroll
    for (int j = 0; j < 4; ++j) o[j] = (short)f2bf(a[j]);
#pragma unroll
    for (int j = 0; j < 4; ++j) o[4 + j] = (short)f2bf(b[j]);
    ((short8*)xb)[i] = o;
}

// ---------------- weight transpose+convert: 64x64 tiles, 16B stores ----------------
__global__ __launch_bounds__(256) void tq_pair(const float* __restrict__ s1,
                                               const float* __restrict__ s3,
                                               unsigned short* __restrict__ dst,
                                               int K, int N,
                                               size_t srcStrideE, size_t dstStrideE) {
    int e = blockIdx.z;
    s1 += (size_t)e * srcStrideE;
    s3 += (size_t)e * srcStrideE;
    dst += (size_t)e * dstStrideE;
    __shared__ unsigned short tile[64][72];
    const int t = threadIdx.x;
    const int k0 = blockIdx.y * 64, n0 = blockIdx.x * 64;
    const int lr = t >> 4, lc4 = (t & 15) * 4;
    const int sr8 = (t & 7) * 8, sn = t >> 3;
#pragma unroll
    for (int half = 0; half < 2; ++half) {
        const float* src = half ? s3 : s1;
#pragma unroll
        for (int r = 0; r < 4; ++r) {
            f32x4 v = *(const f32x4*)(src + (size_t)(k0 + lr + r * 16) * N + n0 + lc4);
#pragma unroll
            for (int j = 0; j < 4; ++j) tile[lr + r * 16][lc4 + j] = f2bf(v[j]);
        }
        __syncthreads();
#pragma unroll
        for (int q = 0; q < 2; ++q) {
            int nn = sn + q * 32;
            int n = n0 + nn;
            int rrow = (n >> 4) * 32 + half * 16 + (n & 15);
            u16x8 o;
#pragma unroll
            for (int j = 0; j < 8; ++j) o[j] = tile[sr8 + j][nn];
            *(u16x8*)(dst + (size_t)rrow * K + k0 + sr8) = o;
        }
        __syncthreads();
    }
}

__global__ __launch_bounds__(256) void tq_plain(const float* __restrict__ src,
                                                unsigned short* __restrict__ dst,
                                                int K, int N,
                                                size_t srcStrideE, size_t dstStrideE) {
    int e = blockIdx.z;
    src += (size_t)e * srcStrideE;
    dst += (size_t)e * dstStrideE;
    __shared__ unsigned short tile[64][72];
    const int t = threadIdx.x;
    const int k0 = blockIdx.y * 64, n0 = blockIdx.x * 64;
    const int lr = t >> 4, lc4 = (t & 15) * 4;
    const int sr8 = (t & 7) * 8, sn = t >> 3;
#pragma unroll
    for (int r = 0; r < 4; ++r) {
        f32x4 v = *(const f32x4*)(src + (size_t)(k0 + lr + r * 16) * N + n0 + lc4);
#pragma unroll
        for (int j = 0; j < 4; ++j) tile[lr + r * 16][lc4 + j] = f2bf(v[j]);
    }
    __syncthreads();
#pragma unroll
    for (int q = 0; q < 2; ++q) {
        int nn = sn + q * 32;
        int n = n0 + nn;
        u16x8 o;
#pragma unroll
        for (int j = 0; j < 8; ++j) o[j] = tile[sr8 + j][nn];
        *(u16x8*)(dst + (size_t)n * K + k0 + sr8) = o;
    }
}

// ---------------- gather: out[t] += sum of 4 routed rows ----------------
__global__ __launch_bounds__(256) void gather_kernel(const float* __restrict__ dbuf,
                                                     const int* __restrict__ rows,
                                                     float* __restrict__ out) {
    const int t = blockIdx.x;
    const int c8 = threadIdx.x * 8;
    int r[4];
#pragma unroll
    for (int k = 0; k < 4; ++k) r[k] = rows[t * 4 + k];
    f32x4 a0, a1;
    {
        const f32x4* z = (const f32x4*)(out + (size_t)t * DIMD + c8);
        a0 = z[0]; a1 = z[1];
    }
#pragma unroll
    for (int k = 0; k < 4; ++k) {
        const f32x4* d = (const f32x4*)(dbuf + (size_t)r[k] * DIMD + c8);
        f32x4 d0 = d[0], d1 = d[1];
#pragma unroll
        for (int j = 0; j < 4; ++j) { a0[j] += d0[j]; a1[j] += d1[j]; }
    }
    f32x4* o = (f32x4*)(out + (size_t)t * DIMD + c8);
    o[0] = a0; o[1] = a1;
}

// ======== fused 128x256 GEMM (R9 core): shared blocks first, then routed ========
// 8 waves (wave tile 64x64), BK=32, LDS 72KB: A 3x8KB @0, B 3x16KB @24576.
// Tri-buffered, staged 2 ahead, vmcnt(3), 1 barrier/K-tile.
// Superrow swizzle: s=r>>1, slot=((r&1)<<2)|(k>>3); phys = s*128+((slot^(s&7))<<4)+(k&7)*2.
template <bool UP>
__global__ __launch_bounds__(512, 2) void gemm_f(
    const unsigned short* __restrict__ Ash, const unsigned short* __restrict__ Art,
    const unsigned short* __restrict__ Bsh, const unsigned short* __restrict__ Brt,
    const int* __restrict__ cnt, const int* __restrict__ offs,
    const int* __restrict__ list, const float* __restrict__ cw,
    unsigned short* __restrict__ hs, unsigned short* __restrict__ hbuf,
    float* __restrict__ fout, float* __restrict__ dbuf,
    const int* __restrict__ table) {
    constexpr int SHBLK = UP ? 512 : 256;

    const int bid = blockIdx.x;
    const bool routed = bid >= SHBLK;
    int bx, rb, e = 0, M, obase = 0;
    const unsigned short* Ap;
    const unsigned short* Bp;
    int ASTRr, BSTRr;
    if (!routed) {
        if (UP) { bx = bid & 15; rb = (bid >> 4) * 128; }
        else    { bx = bid & 7;  rb = (bid >> 3) * 128; }
        M = T_TOK;
        Ap = Ash; Bp = Bsh;
        ASTRr = 2048; BSTRr = 2048;
    } else {
        int rbid = bid - SHBLK;
        int slot = rbid >> 3;
        if (slot >= table[255]) return;
        bx = rbid & 7;
        int pk = table[slot];
        e = pk >> 16; rb = pk & 0xFFFF;
        M = cnt[e]; obase = offs[e];
        Ap = Art;
        Bp = Brt + (UP ? (size_t)e * 2048 * 2048 : (size_t)e * 2048 * 1024);
        ASTRr = UP ? 2048 : 1024;
        BSTRr = UP ? 2048 : 1024;
    }
    const int NT = (!UP && routed) ? 32 : 64;

    extern __shared__ char smem[];

    const int tid = threadIdx.x;
    const int lane = tid & 63, wid = tid >> 6;
    const int wm = wid >> 2, wn = wid & 3;          // wave tile 64x64
    const int fr = lane & 15, fq = lane >> 4;
    const int offR = ((fr >> 1) << 7) + (((((fr & 1) << 2) | fq) ^ (fr >> 1)) << 4);
    const int d16 = tid * 16;

    const unsigned short* pA;
    const unsigned short* pB0;
    const unsigned short* pB1;
    {
        int c = tid, s = c >> 3, sl = (c & 7) ^ (s & 7);
        int rA = 2 * s + (sl >> 2), kk = (sl & 3) * 8;
        int gr = rb + rA;
        int cr = (gr < M) ? gr : (M - 1);
        size_t arow;
        if (!routed)  arow = (size_t)gr;
        else if (UP)  arow = (size_t)list[e * T_TOK + cr];
        else          arow = (size_t)(obase + cr);
        pA = Ap + arow * ASTRr + kk;
    }
#pragma unroll
    for (int u = 0; u < 2; ++u) {
        int c = u * 512 + tid, s = c >> 3, sl = (c & 7) ^ (s & 7);
        int rB = 2 * s + (sl >> 2), kk = (sl & 3) * 8;
        const unsigned short* p = Bp + (size_t)(bx * 256 + rB) * BSTRr + kk;
        if (u == 0) pB0 = p; else pB1 = p;
    }

    f32x4 acc[4][4];
#pragma unroll
    for (int m = 0; m < 4; ++m)
#pragma unroll
        for (int n = 0; n < 4; ++n) acc[m][n] = (f32x4)0.f;

    gload16(pA,      (void*)(smem + 0 + d16));
    gload16(pA + 32, (void*)(smem + 8192 + d16));
    gload16(pB0,      (void*)(smem + 24576 + d16));
    gload16(pB1,      (void*)(smem + 24576 + 8192 + d16));
    gload16(pB0 + 32, (void*)(smem + 24576 + 16384 + d16));
    gload16(pB1 + 32, (void*)(smem + 24576 + 16384 + 8192 + d16));
    pA += 64; pB0 += 64; pB1 += 64;
    asm volatile("s_waitcnt vmcnt(0)" ::: "memory");
    __builtin_amdgcn_s_barrier();

    int bA = 0, bA2 = 16384;
    int bB = 0, bB2 = 32768;
    for (int t = 0; t < NT; ++t) {
        short8 aF[4], bF[4];
#pragma unroll
        for (int m = 0; m < 4; ++m)
            aF[m] = *(const short8*)(smem + bA + wm * 4096 + m * 1024 + offR);
#pragma unroll
        for (int n = 0; n < 4; ++n)
            bF[n] = *(const short8*)(smem + 24576 + bB + wn * 4096 + n * 1024 + offR);
        const bool more = (t + 2 < NT);
        if (more) {
            gload16(pA, (void*)(smem + bA2 + d16));
            gload16(pB0, (void*)(smem + 24576 + bB2 + d16));
            gload16(pB1, (void*)(smem + 24576 + bB2 + 8192 + d16));
            pA += 32; pB0 += 32; pB1 += 32;
        }
        __builtin_amdgcn_s_setprio(1);
#pragma unroll
        for (int m = 0; m < 4; ++m)
#pragma unroll
            for (int n = 0; n < 4; ++n)
                acc[m][n] = __builtin_amdgcn_mfma_f32_16x16x32_bf16(aF[m], bF[n], acc[m][n], 0, 0, 0);
        __builtin_amdgcn_s_setprio(0);
        if (more) { asm volatile("s_waitcnt vmcnt(3)" ::: "memory"); }
        else      { asm volatile("s_waitcnt vmcnt(0)" ::: "memory"); }
        __builtin_amdgcn_s_barrier();
        bA = (bA == 16384) ? 0 : bA + 8192;
        bA2 = (bA2 == 16384) ? 0 : bA2 + 8192;
        bB = (bB == 32768) ? 0 : bB + 16384;
        bB2 = (bB2 == 32768) ? 0 : bB2 + 16384;
    }

    if constexpr (UP) {
        const int LDO = routed ? NI : NSH;
        unsigned short* hp = routed ? hbuf : hs;
#pragma unroll
        for (int m = 0; m < 4; ++m)
#pragma unroll
            for (int q = 0; q < 4; ++q) {
                int gr = rb + wm * 64 + m * 16 + fq * 4 + q;
                if (gr < M) {
                    float coef = routed ? cw[e * T_TOK + gr] : 1.f;
                    size_t orow = (size_t)((routed ? obase : 0) + gr) * LDO;
#pragma unroll
                    for (int nfp = 0; nfp < 2; ++nfp) {
                        float c1 = acc[m][2 * nfp][q], c3 = acc[m][2 * nfp + 1][q];
                        float h = c1 / (1.f + __expf(-c1)) * c3 * coef;
                        int ncol = (bx * 8 + wn * 2 + nfp) * 16 + fr;
                        hp[orow + ncol] = f2bf(h);
                    }
                }
            }
    } else {
#pragma unroll
        for (int m = 0; m < 4; ++m)
#pragma unroll
            for (int q = 0; q < 4; ++q) {
                int gr = rb + wm * 64 + m * 16 + fq * 4 + q;
                if (gr < M) {
                    float* op = routed ? (dbuf + (size_t)(obase + gr) * DIMD)
                                       : (fout + (size_t)gr * DIMD);
#pragma unroll
                    for (int nf = 0; nf < 4; ++nf) {
                        int col = bx * 256 + wn * 64 + nf * 16 + fr;
                        op[col] = acc[m][nf][q];
                    }
                }
            }
    }
}

extern "C" void kernel_launch(void* const* d_in, const int* in_sizes, int n_in,
                              void* d_out, int out_size, void* d_ws, size_t ws_size,
                              hipStream_t stream) {
    const float* x   = (const float*)d_in[0];
    const float* gw  = (const float*)d_in[1];
    const float* w1  = (const float*)d_in[2];
    const float* w2  = (const float*)d_in[3];
    const float* w3  = (const float*)d_in[4];
    const float* ws1 = (const float*)d_in[5];
    const float* ws2 = (const float*)d_in[6];
    const float* ws3 = (const float*)d_in[7];
    float* out = (float*)d_out;

    char* p = (char*)d_ws;
    unsigned short* xb   = (unsigned short*)p; p += (size_t)T_TOK * DIMD * 2;
    unsigned short* hs   = (unsigned short*)p; p += (size_t)T_TOK * NSH * 2;
    unsigned short* hbuf = (unsigned short*)p; p += (size_t)T_TOK * TOPK * NI * 2;
    unsigned short* upT  = (unsigned short*)p; p += (size_t)NEXP * 2048 * DIMD * 2;
    unsigned short* w2T  = (unsigned short*)p; p += (size_t)NEXP * DIMD * NI * 2;
    unsigned short* upsT = (unsigned short*)p; p += (size_t)2 * NSH * DIMD * 2;
    unsigned short* ws2T = (unsigned short*)p; p += (size_t)DIMD * NSH * 2;
    float* gwT = (float*)p;                    p += (size_t)NEXP * DIMD * 4;
    float* cw = (float*)p;                     p += (size_t)NEXP * T_TOK * 4;
    int* list = (int*)p;                       p += (size_t)NEXP * T_TOK * 4;
    int* tk_er = (int*)p;                      p += (size_t)T_TOK * TOPK * 4;
    float* tk_wv = (float*)p;                  p += (size_t)T_TOK * TOPK * 4;
    int* rows = (int*)p;                       p += (size_t)T_TOK * TOPK * 4;
    int* blk_cnt = (int*)p;                    p += (size_t)1024 * 16 * 4;
    int* blk_off = (int*)p;                    p += (size_t)1024 * 16 * 4;
    int* cnt = (int*)p;                        p += 256;
    int* offs = (int*)p;                       p += 256;
    int* table = (int*)p;                      p += 1024;
    if ((size_t)(p - (char*)d_ws) > ws_size) return;
    // dbuf aliases upT (dead after fused-up): 16384*2048*4 == NEXP*2048*DIMD*2
    float* dbuf = (float*)upT;

    hipFuncSetAttribute((const void*)&gemm_f<true>, hipFuncAttributeMaxDynamicSharedMemorySize, 73728);
    hipFuncSetAttribute((const void*)&gemm_f<false>, hipFuncAttributeMaxDynamicSharedMemorySize, 73728);

    gwt_kernel<<<(NEXP * DIMD) / 256, 256, 0, stream>>>(gw, gwT);
    gate_kernel<<<T_TOK / 4, 256, 0, stream>>>(x, gwT, blk_cnt, tk_er, tk_wv);
    scan_kernel<<<1, 256, 0, stream>>>(blk_cnt, blk_off, cnt, offs, table);
    fill_kernel<<<T_TOK * TOPK / 256, 256, 0, stream>>>(tk_er, tk_wv, blk_off, offs,
                                                        list, cw, rows);
    cvt_kernel<<<(T_TOK * DIMD / 8) / 256, 256, 0, stream>>>(x, xb);

    tq_pair<<<dim3(NI / 64, DIMD / 64, NEXP), 256, 0, stream>>>(
        w1, w3, upT, DIMD, NI, (size_t)DIMD * NI, (size_t)2048 * DIMD);
    tq_pair<<<dim3(NSH / 64, DIMD / 64, 1), 256, 0, stream>>>(
        ws1, ws3, upsT, DIMD, NSH, 0, 0);
    tq_plain<<<dim3(DIMD / 64, NI / 64, NEXP), 256, 0, stream>>>(
        w2, w2T, NI, DIMD, (size_t)NI * DIMD, (size_t)DIMD * NI);
    tq_plain<<<dim3(DIMD / 64, NSH / 64, 1), 256, 0, stream>>>(
        ws2, ws2T, NSH, DIMD, 0, 0);

    // fused up: [0,512) shared (16 bx x 32 rb), [512,...) routed slots x 8
    gemm_f<true><<<512 + 144 * 8, 512, 73728, stream>>>(
        xb, xb, upsT, upT, cnt, offs, list, cw, hs, hbuf, nullptr, nullptr, table);
    // fused down: [0,256) shared K=2048 plain-store out; [256,...) routed -> dbuf
    gemm_f<false><<<256 + 144 * 8, 512, 73728, stream>>>(
        hs, hbuf, ws2T, w2T, cnt, offs, list, nullptr, nullptr, nullptr, out, dbuf, table);
    // out[t] += sum of 4 routed rows
    gather_kernel<<<T_TOK, 256, 0, stream>>>(dbuf, rows, out);
}

// Round 13
// 597.944 us; speedup vs baseline: 1.2023x; 1.0495x over previous
//
#include <hip/hip_runtime.h>
#include <hip/hip_bf16.h>
#include <stdint.h>

#define T_TOK 4096
#define DIMD  2048
#define NEXP  16
#define TOPK  4
#define NI    1024
#define NSH   2048

typedef __attribute__((ext_vector_type(8))) short short8;
typedef __attribute__((ext_vector_type(4))) float f32x4;
typedef __attribute__((ext_vector_type(4))) unsigned short u16x4;
typedef __attribute__((ext_vector_type(8))) unsigned short u16x8;

__device__ __forceinline__ unsigned short f2bf(float f) {
    union { float f; unsigned u; } v; v.f = f;
    return (unsigned short)((v.u + 0x7fffu + ((v.u >> 16) & 1u)) >> 16);
}

__device__ __forceinline__ float bf2f(unsigned short b) {
    union { unsigned u; float f; } v; v.u = (unsigned)b << 16;
    return v.f;
}

__device__ __forceinline__ void gload16(const void* g, void* l) {
    __builtin_amdgcn_global_load_lds(
        (const __attribute__((address_space(1))) void*)g,
        (__attribute__((address_space(3))) void*)l, 16, 0, 0);
}

// ---------------- gw transpose ----------------
__global__ __launch_bounds__(256) void gwt_kernel(const float* __restrict__ gw,
                                                  float* __restrict__ gwT) {
    int i = blockIdx.x * 256 + threadIdx.x;
    int d = i >> 4, e = i & 15;
    gwT[e * DIMD + d] = gw[i];
}

// ------- gate: scores + top-4 + LDS-histogram routing + x->bf16 store -------
__global__ __launch_bounds__(256) void gate_kernel(const float* __restrict__ x,
                                                   const float* __restrict__ gwT,
                                                   int* __restrict__ blk_cnt,
                                                   int* __restrict__ tk_er,
                                                   float* __restrict__ tk_wv,
                                                   unsigned short* __restrict__ xb) {
    __shared__ int h[16];
    const int blk = blockIdx.x;
    const int t = blk * 4 + (threadIdx.x >> 6);
    const int lane = threadIdx.x & 63;
    if (threadIdx.x < 16) h[threadIdx.x] = 0;
    __syncthreads();

    const f32x4* xr = (const f32x4*)(x + (size_t)t * DIMD);
    f32x4 xv[8];
#pragma unroll
    for (int i = 0; i < 8; ++i) xv[i] = xr[i * 64 + lane];

    // fused x -> bf16 (each lane owns 8 disjoint 4-elem chunks of the row)
    {
        unsigned short* xo = xb + (size_t)t * DIMD;
#pragma unroll
        for (int i = 0; i < 8; ++i) {
            u16x4 o;
#pragma unroll
            for (int j = 0; j < 4; ++j) o[j] = f2bf(xv[i][j]);
            *(u16x4*)(xo + i * 256 + lane * 4) = o;
        }
    }

    float acc[NEXP];
#pragma unroll
    for (int e = 0; e < NEXP; ++e) {
        const f32x4* gr = (const f32x4*)(gwT + e * DIMD);
        float s = 0.f;
#pragma unroll
        for (int i = 0; i < 8; ++i) {
            f32x4 gv = gr[i * 64 + lane];
            s += xv[i][0] * gv[0] + xv[i][1] * gv[1] +
                 xv[i][2] * gv[2] + xv[i][3] * gv[3];
        }
        acc[e] = s;
    }
#pragma unroll
    for (int e = 0; e < NEXP; ++e) {
        float v = acc[e];
#pragma unroll
        for (int off = 32; off; off >>= 1) v += __shfl_xor(v, off, 64);
        acc[e] = v;
    }
    float m = acc[0];
#pragma unroll
    for (int e = 1; e < NEXP; ++e) m = fmaxf(m, acc[e]);
    float s = 0.f;
#pragma unroll
    for (int e = 0; e < NEXP; ++e) { acc[e] = expf(acc[e] - m); s += acc[e]; }
    float inv = 1.f / s;
#pragma unroll
    for (int e = 0; e < NEXP; ++e) acc[e] *= inv;

    float w4[TOPK]; int i4[TOPK];
#pragma unroll
    for (int k = 0; k < TOPK; ++k) {
        float bv = -1.f; int be = 0;
#pragma unroll
        for (int e = 0; e < NEXP; ++e)
            if (acc[e] > bv) { bv = acc[e]; be = e; }
        w4[k] = bv; i4[k] = be;
#pragma unroll
        for (int e = 0; e < NEXP; ++e)
            if (e == be) acc[e] = -1.f;
    }

    if (lane == 0) {
        int r4[TOPK];
#pragma unroll
        for (int k = 0; k < TOPK; ++k) r4[k] = atomicAdd(&h[i4[k]], 1);
#pragma unroll
        for (int k = 0; k < TOPK; ++k) {
            tk_er[t * 4 + k] = (i4[k] << 20) | r4[k];
            tk_wv[t * 4 + k] = w4[k];
        }
    }
    __syncthreads();
    if (threadIdx.x < 16) blk_cnt[blk * 16 + threadIdx.x] = h[threadIdx.x];
}

// ---------------- hierarchical scan; slot table at BM=128 ----------------
__global__ __launch_bounds__(256) void scan_kernel(const int* __restrict__ blk_cnt,
                                                   int* __restrict__ blk_off,
                                                   int* __restrict__ cnt,
                                                   int* __restrict__ offs,
                                                   int* __restrict__ table) {
    __shared__ int gsum[16][17];
    __shared__ int gbase[16][17];
    __shared__ int csh[16];
    int tid = threadIdx.x;
    int e = tid >> 4, g = tid & 15;
    {
        int s = 0;
        for (int b = g * 64; b < g * 64 + 64; ++b) s += blk_cnt[b * 16 + e];
        gsum[e][g] = s;
    }
    __syncthreads();
    if (tid < 16) {
        int run = 0;
        for (int g2 = 0; g2 < 16; ++g2) { gbase[tid][g2] = run; run += gsum[tid][g2]; }
        csh[tid] = run;
        cnt[tid] = run;
    }
    __syncthreads();
    {
        int run = gbase[e][g];
        for (int b = g * 64; b < g * 64 + 64; ++b) {
            blk_off[b * 16 + e] = run;
            run += blk_cnt[b * 16 + e];
        }
    }
    if (tid == 0) {
        int o = 0;
        for (int e2 = 0; e2 < 16; ++e2) { offs[e2] = o; o += csh[e2]; }
        offs[NEXP] = o;
        int ns = 0;
        for (int e2 = 0; e2 < 16; ++e2)
            for (int rb = 0; rb < csh[e2]; rb += 128) {
                table[ns] = (e2 << 16) | rb; ++ns;
            }
        table[255] = ns;
    }
}

// ---------------- fill compacted expert lists + token->row table ----------------
__global__ __launch_bounds__(256) void fill_kernel(const int* __restrict__ tk_er,
                                                   const float* __restrict__ tk_wv,
                                                   const int* __restrict__ blk_off,
                                                   const int* __restrict__ offs,
                                                   int* __restrict__ list,
                                                   float* __restrict__ cw,
                                                   int* __restrict__ rows) {
    int i = blockIdx.x * 256 + threadIdx.x;
    int rec = tk_er[i];
    int e = rec >> 20, r = rec & 0xFFFFF;
    int t = i >> 2;
    int ro = blk_off[(t >> 2) * 16 + e] + r;
    list[e * T_TOK + ro] = t;
    cw[e * T_TOK + ro] = tk_wv[i];
    rows[i] = offs[e] + ro;
}

// ---------------- weight transpose+convert: 64x64 tiles, 16B stores ----------------
__global__ __launch_bounds__(256) void tq_pair(const float* __restrict__ s1,
                                               const float* __restrict__ s3,
                                               unsigned short* __restrict__ dst,
                                               int K, int N,
                                               size_t srcStrideE, size_t dstStrideE) {
    int e = blockIdx.z;
    s1 += (size_t)e * srcStrideE;
    s3 += (size_t)e * srcStrideE;
    dst += (size_t)e * dstStrideE;
    __shared__ unsigned short tile[64][72];
    const int t = threadIdx.x;
    const int k0 = blockIdx.y * 64, n0 = blockIdx.x * 64;
    const int lr = t >> 4, lc4 = (t & 15) * 4;
    const int sr8 = (t & 7) * 8, sn = t >> 3;
#pragma unroll
    for (int half = 0; half < 2; ++half) {
        const float* src = half ? s3 : s1;
#pragma unroll
        for (int r = 0; r < 4; ++r) {
            f32x4 v = *(const f32x4*)(src + (size_t)(k0 + lr + r * 16) * N + n0 + lc4);
#pragma unroll
            for (int j = 0; j < 4; ++j) tile[lr + r * 16][lc4 + j] = f2bf(v[j]);
        }
        __syncthreads();
#pragma unroll
        for (int q = 0; q < 2; ++q) {
            int nn = sn + q * 32;
            int n = n0 + nn;
            int rrow = (n >> 4) * 32 + half * 16 + (n & 15);
            u16x8 o;
#pragma unroll
            for (int j = 0; j < 8; ++j) o[j] = tile[sr8 + j][nn];
            *(u16x8*)(dst + (size_t)rrow * K + k0 + sr8) = o;
        }
        __syncthreads();
    }
}

__global__ __launch_bounds__(256) void tq_plain(const float* __restrict__ src,
                                                unsigned short* __restrict__ dst,
                                                int K, int N,
                                                size_t srcStrideE, size_t dstStrideE) {
    int e = blockIdx.z;
    src += (size_t)e * srcStrideE;
    dst += (size_t)e * dstStrideE;
    __shared__ unsigned short tile[64][72];
    const int t = threadIdx.x;
    const int k0 = blockIdx.y * 64, n0 = blockIdx.x * 64;
    const int lr = t >> 4, lc4 = (t & 15) * 4;
    const int sr8 = (t & 7) * 8, sn = t >> 3;
#pragma unroll
    for (int r = 0; r < 4; ++r) {
        f32x4 v = *(const f32x4*)(src + (size_t)(k0 + lr + r * 16) * N + n0 + lc4);
#pragma unroll
        for (int j = 0; j < 4; ++j) tile[lr + r * 16][lc4 + j] = f2bf(v[j]);
    }
    __syncthreads();
#pragma unroll
    for (int q = 0; q < 2; ++q) {
        int nn = sn + q * 32;
        int n = n0 + nn;
        u16x8 o;
#pragma unroll
        for (int j = 0; j < 8; ++j) o[j] = tile[sr8 + j][nn];
        *(u16x8*)(dst + (size_t)n * K + k0 + sr8) = o;
    }
}

// ---------------- gather: out[t] += sum of 4 routed rows (bf16 dbuf) ----------------
__global__ __launch_bounds__(256) void gather_kernel(const unsigned short* __restrict__ dbuf,
                                                     const int* __restrict__ rows,
                                                     float* __restrict__ out) {
    const int t = blockIdx.x;
    const int c8 = threadIdx.x * 8;
    int r[4];
#pragma unroll
    for (int k = 0; k < 4; ++k) r[k] = rows[t * 4 + k];
    f32x4 a0, a1;
    {
        const f32x4* z = (const f32x4*)(out + (size_t)t * DIMD + c8);
        a0 = z[0]; a1 = z[1];
    }
#pragma unroll
    for (int k = 0; k < 4; ++k) {
        u16x8 d = *(const u16x8*)(dbuf + (size_t)r[k] * DIMD + c8);
#pragma unroll
        for (int j = 0; j < 4; ++j) { a0[j] += bf2f(d[j]); a1[j] += bf2f(d[4 + j]); }
    }
    f32x4* o = (f32x4*)(out + (size_t)t * DIMD + c8);
    o[0] = a0; o[1] = a1;
}

// ======== fused 128x256 GEMM (R9 core): shared blocks first, then routed ========
// 8 waves (wave tile 64x64), BK=32, LDS 72KB: A 3x8KB @0, B 3x16KB @24576.
// Tri-buffered, staged 2 ahead, vmcnt(3), 1 barrier/K-tile.
// Superrow swizzle: s=r>>1, slot=((r&1)<<2)|(k>>3); phys = s*128+((slot^(s&7))<<4)+(k&7)*2.
template <bool UP>
__global__ __launch_bounds__(512, 2) void gemm_f(
    const unsigned short* __restrict__ Ash, const unsigned short* __restrict__ Art,
    const unsigned short* __restrict__ Bsh, const unsigned short* __restrict__ Brt,
    const int* __restrict__ cnt, const int* __restrict__ offs,
    const int* __restrict__ list, const float* __restrict__ cw,
    unsigned short* __restrict__ hs, unsigned short* __restrict__ hbuf,
    float* __restrict__ fout, unsigned short* __restrict__ dbuf,
    const int* __restrict__ table) {
    constexpr int SHBLK = UP ? 512 : 256;

    const int bid = blockIdx.x;
    const bool routed = bid >= SHBLK;
    int bx, rb, e = 0, M, obase = 0;
    const unsigned short* Ap;
    const unsigned short* Bp;
    int ASTRr, BSTRr;
    if (!routed) {
        if (UP) { bx = bid & 15; rb = (bid >> 4) * 128; }
        else    { bx = bid & 7;  rb = (bid >> 3) * 128; }
        M = T_TOK;
        Ap = Ash; Bp = Bsh;
        ASTRr = 2048; BSTRr = 2048;
    } else {
        int rbid = bid - SHBLK;
        int slot = rbid >> 3;
        if (slot >= table[255]) return;
        bx = rbid & 7;
        int pk = table[slot];
        e = pk >> 16; rb = pk & 0xFFFF;
        M = cnt[e]; obase = offs[e];
        Ap = Art;
        Bp = Brt + (UP ? (size_t)e * 2048 * 2048 : (size_t)e * 2048 * 1024);
        ASTRr = UP ? 2048 : 1024;
        BSTRr = UP ? 2048 : 1024;
    }
    const int NT = (!UP && routed) ? 32 : 64;

    extern __shared__ char smem[];

    const int tid = threadIdx.x;
    const int lane = tid & 63, wid = tid >> 6;
    const int wm = wid >> 2, wn = wid & 3;          // wave tile 64x64
    const int fr = lane & 15, fq = lane >> 4;
    const int offR = ((fr >> 1) << 7) + (((((fr & 1) << 2) | fq) ^ (fr >> 1)) << 4);
    const int d16 = tid * 16;

    const unsigned short* pA;
    const unsigned short* pB0;
    const unsigned short* pB1;
    {
        int c = tid, s = c >> 3, sl = (c & 7) ^ (s & 7);
        int rA = 2 * s + (sl >> 2), kk = (sl & 3) * 8;
        int gr = rb + rA;
        int cr = (gr < M) ? gr : (M - 1);
        size_t arow;
        if (!routed)  arow = (size_t)gr;
        else if (UP)  arow = (size_t)list[e * T_TOK + cr];
        else          arow = (size_t)(obase + cr);
        pA = Ap + arow * ASTRr + kk;
    }
#pragma unroll
    for (int u = 0; u < 2; ++u) {
        int c = u * 512 + tid, s = c >> 3, sl = (c & 7) ^ (s & 7);
        int rB = 2 * s + (sl >> 2), kk = (sl & 3) * 8;
        const unsigned short* p = Bp + (size_t)(bx * 256 + rB) * BSTRr + kk;
        if (u == 0) pB0 = p; else pB1 = p;
    }

    f32x4 acc[4][4];
#pragma unroll
    for (int m = 0; m < 4; ++m)
#pragma unroll
        for (int n = 0; n < 4; ++n) acc[m][n] = (f32x4)0.f;

    gload16(pA,      (void*)(smem + 0 + d16));
    gload16(pA + 32, (void*)(smem + 8192 + d16));
    gload16(pB0,      (void*)(smem + 24576 + d16));
    gload16(pB1,      (void*)(smem + 24576 + 8192 + d16));
    gload16(pB0 + 32, (void*)(smem + 24576 + 16384 + d16));
    gload16(pB1 + 32, (void*)(smem + 24576 + 16384 + 8192 + d16));
    pA += 64; pB0 += 64; pB1 += 64;
    asm volatile("s_waitcnt vmcnt(0)" ::: "memory");
    __builtin_amdgcn_s_barrier();

    int bA = 0, bA2 = 16384;
    int bB = 0, bB2 = 32768;
    for (int t = 0; t < NT; ++t) {
        short8 aF[4], bF[4];
#pragma unroll
        for (int m = 0; m < 4; ++m)
            aF[m] = *(const short8*)(smem + bA + wm * 4096 + m * 1024 + offR);
#pragma unroll
        for (int n = 0; n < 4; ++n)
            bF[n] = *(const short8*)(smem + 24576 + bB + wn * 4096 + n * 1024 + offR);
        const bool more = (t + 2 < NT);
        if (more) {
            gload16(pA, (void*)(smem + bA2 + d16));
            gload16(pB0, (void*)(smem + 24576 + bB2 + d16));
            gload16(pB1, (void*)(smem + 24576 + bB2 + 8192 + d16));
            pA += 32; pB0 += 32; pB1 += 32;
        }
        __builtin_amdgcn_s_setprio(1);
#pragma unroll
        for (int m = 0; m < 4; ++m)
#pragma unroll
            for (int n = 0; n < 4; ++n)
                acc[m][n] = __builtin_amdgcn_mfma_f32_16x16x32_bf16(aF[m], bF[n], acc[m][n], 0, 0, 0);
        __builtin_amdgcn_s_setprio(0);
        if (more) { asm volatile("s_waitcnt vmcnt(3)" ::: "memory"); }
        else      { asm volatile("s_waitcnt vmcnt(0)" ::: "memory"); }
        __builtin_amdgcn_s_barrier();
        bA = (bA == 16384) ? 0 : bA + 8192;
        bA2 = (bA2 == 16384) ? 0 : bA2 + 8192;
        bB = (bB == 32768) ? 0 : bB + 16384;
        bB2 = (bB2 == 32768) ? 0 : bB2 + 16384;
    }

    if constexpr (UP) {
        const int LDO = routed ? NI : NSH;
        unsigned short* hp = routed ? hbuf : hs;
#pragma unroll
        for (int m = 0; m < 4; ++m)
#pragma unroll
            for (int q = 0; q < 4; ++q) {
                int gr = rb + wm * 64 + m * 16 + fq * 4 + q;
                if (gr < M) {
                    float coef = routed ? cw[e * T_TOK + gr] : 1.f;
                    size_t orow = (size_t)((routed ? obase : 0) + gr) * LDO;
#pragma unroll
                    for (int nfp = 0; nfp < 2; ++nfp) {
                        float c1 = acc[m][2 * nfp][q], c3 = acc[m][2 * nfp + 1][q];
                        float h = c1 / (1.f + __expf(-c1)) * c3 * coef;
                        int ncol = (bx * 8 + wn * 2 + nfp) * 16 + fr;
                        hp[orow + ncol] = f2bf(h);
                    }
                }
            }
    } else {
#pragma unroll
        for (int m = 0; m < 4; ++m)
#pragma unroll
            for (int q = 0; q < 4; ++q) {
                int gr = rb + wm * 64 + m * 16 + fq * 4 + q;
                if (gr < M) {
                    if (routed) {
                        unsigned short* op = dbuf + (size_t)(obase + gr) * DIMD;
#pragma unroll
                        for (int nf = 0; nf < 4; ++nf) {
                            int col = bx * 256 + wn * 64 + nf * 16 + fr;
                            op[col] = f2bf(acc[m][nf][q]);
                        }
                    } else {
                        float* op = fout + (size_t)gr * DIMD;
#pragma unroll
                        for (int nf = 0; nf < 4; ++nf) {
                            int col = bx * 256 + wn * 64 + nf * 16 + fr;
                            op[col] = acc[m][nf][q];
                        }
                    }
                }
            }
    }
}

extern "C" void kernel_launch(void* const* d_in, const int* in_sizes, int n_in,
                              void* d_out, int out_size, void* d_ws, size_t ws_size,
                              hipStream_t stream) {
    const float* x   = (const float*)d_in[0];
    const float* gw  = (const float*)d_in[1];
    const float* w1  = (const float*)d_in[2];
    const float* w2  = (const float*)d_in[3];
    const float* w3  = (const float*)d_in[4];
    const float* ws1 = (const float*)d_in[5];
    const float* ws2 = (const float*)d_in[6];
    const float* ws3 = (const float*)d_in[7];
    float* out = (float*)d_out;

    char* p = (char*)d_ws;
    unsigned short* xb   = (unsigned short*)p; p += (size_t)T_TOK * DIMD * 2;
    unsigned short* hs   = (unsigned short*)p; p += (size_t)T_TOK * NSH * 2;
    unsigned short* hbuf = (unsigned short*)p; p += (size_t)T_TOK * TOPK * NI * 2;
    unsigned short* upT  = (unsigned short*)p; p += (size_t)NEXP * 2048 * DIMD * 2;
    unsigned short* w2T  = (unsigned short*)p; p += (size_t)NEXP * DIMD * NI * 2;
    unsigned short* upsT = (unsigned short*)p; p += (size_t)2 * NSH * DIMD * 2;
    unsigned short* ws2T = (unsigned short*)p; p += (size_t)DIMD * NSH * 2;
    float* gwT = (float*)p;                    p += (size_t)NEXP * DIMD * 4;
    float* cw = (float*)p;                     p += (size_t)NEXP * T_TOK * 4;
    int* list = (int*)p;                       p += (size_t)NEXP * T_TOK * 4;
    int* tk_er = (int*)p;                      p += (size_t)T_TOK * TOPK * 4;
    float* tk_wv = (float*)p;                  p += (size_t)T_TOK * TOPK * 4;
    int* rows = (int*)p;                       p += (size_t)T_TOK * TOPK * 4;
    int* blk_cnt = (int*)p;                    p += (size_t)1024 * 16 * 4;
    int* blk_off = (int*)p;                    p += (size_t)1024 * 16 * 4;
    int* cnt = (int*)p;                        p += 256;
    int* offs = (int*)p;                       p += 256;
    int* table = (int*)p;                      p += 1024;
    if ((size_t)(p - (char*)d_ws) > ws_size) return;
    // dbuf (bf16, 67MB) aliases upT (134MB, dead after fused-up)
    unsigned short* dbuf = upT;

    hipFuncSetAttribute((const void*)&gemm_f<true>, hipFuncAttributeMaxDynamicSharedMemorySize, 73728);
    hipFuncSetAttribute((const void*)&gemm_f<false>, hipFuncAttributeMaxDynamicSharedMemorySize, 73728);

    gwt_kernel<<<(NEXP * DIMD) / 256, 256, 0, stream>>>(gw, gwT);
    gate_kernel<<<T_TOK / 4, 256, 0, stream>>>(x, gwT, blk_cnt, tk_er, tk_wv, xb);
    scan_kernel<<<1, 256, 0, stream>>>(blk_cnt, blk_off, cnt, offs, table);
    fill_kernel<<<T_TOK * TOPK / 256, 256, 0, stream>>>(tk_er, tk_wv, blk_off, offs,
                                                        list, cw, rows);

    tq_pair<<<dim3(NI / 64, DIMD / 64, NEXP), 256, 0, stream>>>(
        w1, w3, upT, DIMD, NI, (size_t)DIMD * NI, (size_t)2048 * DIMD);
    tq_pair<<<dim3(NSH / 64, DIMD / 64, 1), 256, 0, stream>>>(
        ws1, ws3, upsT, DIMD, NSH, 0, 0);
    tq_plain<<<dim3(DIMD / 64, NI / 64, NEXP), 256, 0, stream>>>(
        w2, w2T, NI, DIMD, (size_t)NI * DIMD, (size_t)DIMD * NI);
    tq_plain<<<dim3(DIMD / 64, NSH / 64, 1), 256, 0, stream>>>(
        ws2, ws2T, NSH, DIMD, 0, 0);

    // fused up: [0,512) shared (16 bx x 32 rb), [512,...) routed slots x 8
    gemm_f<true><<<512 + 144 * 8, 512, 73728, stream>>>(
        xb, xb, upsT, upT, cnt, offs, list, cw, hs, hbuf, nullptr, nullptr, table);
    // fused down: [0,256) shared K=2048 plain-store out; [256,...) routed -> bf16 dbuf
    gemm_f<false><<<256 + 144 * 8, 512, 73728, stream>>>(
        hs, hbuf, ws2T, w2T, cnt, offs, list, nullptr, nullptr, nullptr, out, dbuf, table);
    // out[t] += sum of 4 routed rows
    gather_kernel<<<T_TOK, 256, 0, stream>>>(dbuf, rows, out);
}

// Round 14
// 591.272 us; speedup vs baseline: 1.2159x; 1.0113x over previous
//
#include <hip/hip_runtime.h>
#include <hip/hip_bf16.h>
#include <stdint.h>

#define T_TOK 4096
#define DIMD  2048
#define NEXP  16
#define TOPK  4
#define NI    1024
#define NSH   2048
#define TCAP  320   // per-XCD-class routed block capacity

typedef __attribute__((ext_vector_type(8))) short short8;
typedef __attribute__((ext_vector_type(4))) float f32x4;
typedef __attribute__((ext_vector_type(4))) unsigned short u16x4;
typedef __attribute__((ext_vector_type(8))) unsigned short u16x8;

__device__ __forceinline__ unsigned short f2bf(float f) {
    union { float f; unsigned u; } v; v.f = f;
    return (unsigned short)((v.u + 0x7fffu + ((v.u >> 16) & 1u)) >> 16);
}

__device__ __forceinline__ float bf2f(unsigned short b) {
    union { unsigned u; float f; } v; v.u = (unsigned)b << 16;
    return v.f;
}

__device__ __forceinline__ void gload16(const void* g, void* l) {
    __builtin_amdgcn_global_load_lds(
        (const __attribute__((address_space(1))) void*)g,
        (__attribute__((address_space(3))) void*)l, 16, 0, 0);
}

// ---------------- gw transpose ----------------
__global__ __launch_bounds__(256) void gwt_kernel(const float* __restrict__ gw,
                                                  float* __restrict__ gwT) {
    int i = blockIdx.x * 256 + threadIdx.x;
    int d = i >> 4, e = i & 15;
    gwT[e * DIMD + d] = gw[i];
}

// ------- gate: scores + top-4 + LDS-histogram routing + x->bf16 store -------
__global__ __launch_bounds__(256) void gate_kernel(const float* __restrict__ x,
                                                   const float* __restrict__ gwT,
                                                   int* __restrict__ blk_cnt,
                                                   int* __restrict__ tk_er,
                                                   float* __restrict__ tk_wv,
                                                   unsigned short* __restrict__ xb) {
    __shared__ int h[16];
    const int blk = blockIdx.x;
    const int t = blk * 4 + (threadIdx.x >> 6);
    const int lane = threadIdx.x & 63;
    if (threadIdx.x < 16) h[threadIdx.x] = 0;
    __syncthreads();

    const f32x4* xr = (const f32x4*)(x + (size_t)t * DIMD);
    f32x4 xv[8];
#pragma unroll
    for (int i = 0; i < 8; ++i) xv[i] = xr[i * 64 + lane];

    {
        unsigned short* xo = xb + (size_t)t * DIMD;
#pragma unroll
        for (int i = 0; i < 8; ++i) {
            u16x4 o;
#pragma unroll
            for (int j = 0; j < 4; ++j) o[j] = f2bf(xv[i][j]);
            *(u16x4*)(xo + i * 256 + lane * 4) = o;
        }
    }

    float acc[NEXP];
#pragma unroll
    for (int e = 0; e < NEXP; ++e) {
        const f32x4* gr = (const f32x4*)(gwT + e * DIMD);
        float s = 0.f;
#pragma unroll
        for (int i = 0; i < 8; ++i) {
            f32x4 gv = gr[i * 64 + lane];
            s += xv[i][0] * gv[0] + xv[i][1] * gv[1] +
                 xv[i][2] * gv[2] + xv[i][3] * gv[3];
        }
        acc[e] = s;
    }
#pragma unroll
    for (int e = 0; e < NEXP; ++e) {
        float v = acc[e];
#pragma unroll
        for (int off = 32; off; off >>= 1) v += __shfl_xor(v, off, 64);
        acc[e] = v;
    }
    float m = acc[0];
#pragma unroll
    for (int e = 1; e < NEXP; ++e) m = fmaxf(m, acc[e]);
    float s = 0.f;
#pragma unroll
    for (int e = 0; e < NEXP; ++e) { acc[e] = expf(acc[e] - m); s += acc[e]; }
    float inv = 1.f / s;
#pragma unroll
    for (int e = 0; e < NEXP; ++e) acc[e] *= inv;

    float w4[TOPK]; int i4[TOPK];
#pragma unroll
    for (int k = 0; k < TOPK; ++k) {
        float bv = -1.f; int be = 0;
#pragma unroll
        for (int e = 0; e < NEXP; ++e)
            if (acc[e] > bv) { bv = acc[e]; be = e; }
        w4[k] = bv; i4[k] = be;
#pragma unroll
        for (int e = 0; e < NEXP; ++e)
            if (e == be) acc[e] = -1.f;
    }

    if (lane == 0) {
        int r4[TOPK];
#pragma unroll
        for (int k = 0; k < TOPK; ++k) r4[k] = atomicAdd(&h[i4[k]], 1);
#pragma unroll
        for (int k = 0; k < TOPK; ++k) {
            tk_er[t * 4 + k] = (i4[k] << 20) | r4[k];
            tk_wv[t * 4 + k] = w4[k];
        }
    }
    __syncthreads();
    if (threadIdx.x < 16) blk_cnt[blk * 16 + threadIdx.x] = h[threadIdx.x];
}

// ---- hierarchical scan + XCD-class routed block table (class = expert&7) ----
// table[i] valid iff i%8 == e%8: entry = (e<<16)|(bx<<13)|rb, -1 if empty.
// Within a class: bx inner, slot next, expert (c then c+8) outer.
__global__ __launch_bounds__(256) void scan_kernel(const int* __restrict__ blk_cnt,
                                                   int* __restrict__ blk_off,
                                                   int* __restrict__ cnt,
                                                   int* __restrict__ offs,
                                                   int* __restrict__ table) {
    __shared__ int gsum[16][17];
    __shared__ int gbase[16][17];
    __shared__ int csh[16];
    int tid = threadIdx.x;
    int e = tid >> 4, g = tid & 15;
    {
        int s = 0;
        for (int b = g * 64; b < g * 64 + 64; ++b) s += blk_cnt[b * 16 + e];
        gsum[e][g] = s;
    }
    __syncthreads();
    if (tid < 16) {
        int run = 0;
        for (int g2 = 0; g2 < 16; ++g2) { gbase[tid][g2] = run; run += gsum[tid][g2]; }
        csh[tid] = run;
        cnt[tid] = run;
    }
    __syncthreads();
    {
        int run = gbase[e][g];
        for (int b = g * 64; b < g * 64 + 64; ++b) {
            blk_off[b * 16 + e] = run;
            run += blk_cnt[b * 16 + e];
        }
    }
    if (tid == 0) {
        int o = 0;
        for (int e2 = 0; e2 < 16; ++e2) { offs[e2] = o; o += csh[e2]; }
        offs[NEXP] = o;
    }
    __syncthreads();
    for (int idx = tid; idx < 8 * TCAP; idx += 256) {
        int c = idx & 7, j = idx >> 3;
        int n0 = ((csh[c] + 127) >> 7) << 3;       // blocks of expert c
        int n1 = ((csh[c + 8] + 127) >> 7) << 3;   // blocks of expert c+8
        int v = -1;
        if (j < n0)
            v = (c << 16) | ((j & 7) << 13) | ((j >> 3) * 128);
        else if (j < n0 + n1) {
            int j2 = j - n0;
            v = ((c + 8) << 16) | ((j2 & 7) << 13) | ((j2 >> 3) * 128);
        }
        table[idx] = v;
    }
}

// ---------------- fill compacted expert lists + token->row table ----------------
__global__ __launch_bounds__(256) void fill_kernel(const int* __restrict__ tk_er,
                                                   const float* __restrict__ tk_wv,
                                                   const int* __restrict__ blk_off,
                                                   const int* __restrict__ offs,
                                                   int* __restrict__ list,
                                                   float* __restrict__ cw,
                                                   int* __restrict__ rows) {
    int i = blockIdx.x * 256 + threadIdx.x;
    int rec = tk_er[i];
    int e = rec >> 20, r = rec & 0xFFFFF;
    int t = i >> 2;
    int ro = blk_off[(t >> 2) * 16 + e] + r;
    list[e * T_TOK + ro] = t;
    cw[e * T_TOK + ro] = tk_wv[i];
    rows[i] = offs[e] + ro;
}

// ---------------- weight transpose+convert: 64x64 tiles, 16B stores ----------------
__global__ __launch_bounds__(256) void tq_pair(const float* __restrict__ s1,
                                               const float* __restrict__ s3,
                                               unsigned short* __restrict__ dst,
                                               int K, int N,
                                               size_t srcStrideE, size_t dstStrideE) {
    int e = blockIdx.z;
    s1 += (size_t)e * srcStrideE;
    s3 += (size_t)e * srcStrideE;
    dst += (size_t)e * dstStrideE;
    __shared__ unsigned short tile[64][72];
    const int t = threadIdx.x;
    const int k0 = blockIdx.y * 64, n0 = blockIdx.x * 64;
    const int lr = t >> 4, lc4 = (t & 15) * 4;
    const int sr8 = (t & 7) * 8, sn = t >> 3;
#pragma unroll
    for (int half = 0; half < 2; ++half) {
        const float* src = half ? s3 : s1;
#pragma unroll
        for (int r = 0; r < 4; ++r) {
            f32x4 v = *(const f32x4*)(src + (size_t)(k0 + lr + r * 16) * N + n0 + lc4);
#pragma unroll
            for (int j = 0; j < 4; ++j) tile[lr + r * 16][lc4 + j] = f2bf(v[j]);
        }
        __syncthreads();
#pragma unroll
        for (int q = 0; q < 2; ++q) {
            int nn = sn + q * 32;
            int n = n0 + nn;
            int rrow = (n >> 4) * 32 + half * 16 + (n & 15);
            u16x8 o;
#pragma unroll
            for (int j = 0; j < 8; ++j) o[j] = tile[sr8 + j][nn];
            *(u16x8*)(dst + (size_t)rrow * K + k0 + sr8) = o;
        }
        __syncthreads();
    }
}

__global__ __launch_bounds__(256) void tq_plain(const float* __restrict__ src,
                                                unsigned short* __restrict__ dst,
                                                int K, int N,
                                                size_t srcStrideE, size_t dstStrideE) {
    int e = blockIdx.z;
    src += (size_t)e * srcStrideE;
    dst += (size_t)e * dstStrideE;
    __shared__ unsigned short tile[64][72];
    const int t = threadIdx.x;
    const int k0 = blockIdx.y * 64, n0 = blockIdx.x * 64;
    const int lr = t >> 4, lc4 = (t & 15) * 4;
    const int sr8 = (t & 7) * 8, sn = t >> 3;
#pragma unroll
    for (int r = 0; r < 4; ++r) {
        f32x4 v = *(const f32x4*)(src + (size_t)(k0 + lr + r * 16) * N + n0 + lc4);
#pragma unroll
        for (int j = 0; j < 4; ++j) tile[lr + r * 16][lc4 + j] = f2bf(v[j]);
    }
    __syncthreads();
#pragma unroll
    for (int q = 0; q < 2; ++q) {
        int nn = sn + q * 32;
        int n = n0 + nn;
        u16x8 o;
#pragma unroll
        for (int j = 0; j < 8; ++j) o[j] = tile[sr8 + j][nn];
        *(u16x8*)(dst + (size_t)n * K + k0 + sr8) = o;
    }
}

// ---------------- gather: out[t] += sum of 4 routed rows (bf16 dbuf) ----------------
__global__ __launch_bounds__(256) void gather_kernel(const unsigned short* __restrict__ dbuf,
                                                     const int* __restrict__ rows,
                                                     float* __restrict__ out) {
    const int t = blockIdx.x;
    const int c8 = threadIdx.x * 8;
    int r[4];
#pragma unroll
    for (int k = 0; k < 4; ++k) r[k] = rows[t * 4 + k];
    f32x4 a0, a1;
    {
        const f32x4* z = (const f32x4*)(out + (size_t)t * DIMD + c8);
        a0 = z[0]; a1 = z[1];
    }
#pragma unroll
    for (int k = 0; k < 4; ++k) {
        u16x8 d = *(const u16x8*)(dbuf + (size_t)r[k] * DIMD + c8);
#pragma unroll
        for (int j = 0; j < 4; ++j) { a0[j] += bf2f(d[j]); a1[j] += bf2f(d[4 + j]); }
    }
    f32x4* o = (f32x4*)(out + (size_t)t * DIMD + c8);
    o[0] = a0; o[1] = a1;
}

// ======== fused 128x256 GEMM (R9 core), XCD-class block mapping ========
// 8 waves (wave tile 64x64), BK=32, LDS 72KB: A 3x8KB @0, B 3x16KB @24576.
// Tri-buffered, staged 2 ahead, vmcnt(3), 1 barrier/K-tile.
// Superrow swizzle: s=r>>1, slot=((r&1)<<2)|(k>>3); phys = s*128+((slot^(s&7))<<4)+(k&7)*2.
template <bool UP>
__global__ __launch_bounds__(512, 2) void gemm_f(
    const unsigned short* __restrict__ Ash, const unsigned short* __restrict__ Art,
    const unsigned short* __restrict__ Bsh, const unsigned short* __restrict__ Brt,
    const int* __restrict__ cnt, const int* __restrict__ offs,
    const int* __restrict__ list, const float* __restrict__ cw,
    unsigned short* __restrict__ hs, unsigned short* __restrict__ hbuf,
    float* __restrict__ fout, unsigned short* __restrict__ dbuf,
    const int* __restrict__ table) {
    constexpr int SHBLK = UP ? 512 : 256;

    const int bid = blockIdx.x;
    const bool routed = bid >= SHBLK;
    int bx, rb, e = 0, M, obase = 0;
    const unsigned short* Ap;
    const unsigned short* Bp;
    int ASTRr, BSTRr;
    if (!routed) {
        if (UP) { bx = bid & 15; rb = (bid >> 4) * 128; }
        else    { bx = bid >> 5; rb = (bid & 31) * 128; }   // bx-major: same-rb co-XCD
        M = T_TOK;
        Ap = Ash; Bp = Bsh;
        ASTRr = 2048; BSTRr = 2048;
    } else {
        int pk = table[bid - SHBLK];   // (bid-SHBLK)%8 == e%8 == XCD class
        if (pk < 0) return;
        e = pk >> 16; bx = (pk >> 13) & 7; rb = pk & 8191;
        M = cnt[e]; obase = offs[e];
        Ap = Art;
        Bp = Brt + (UP ? (size_t)e * 2048 * 2048 : (size_t)e * 2048 * 1024);
        ASTRr = UP ? 2048 : 1024;
        BSTRr = UP ? 2048 : 1024;
    }
    const int NT = (!UP && routed) ? 32 : 64;

    extern __shared__ char smem[];

    const int tid = threadIdx.x;
    const int lane = tid & 63, wid = tid >> 6;
    const int wm = wid >> 2, wn = wid & 3;          // wave tile 64x64
    const int fr = lane & 15, fq = lane >> 4;
    const int offR = ((fr >> 1) << 7) + (((((fr & 1) << 2) | fq) ^ (fr >> 1)) << 4);
    const int d16 = tid * 16;

    const unsigned short* pA;
    const unsigned short* pB0;
    const unsigned short* pB1;
    {
        int c = tid, s = c >> 3, sl = (c & 7) ^ (s & 7);
        int rA = 2 * s + (sl >> 2), kk = (sl & 3) * 8;
        int gr = rb + rA;
        int cr = (gr < M) ? gr : (M - 1);
        size_t arow;
        if (!routed)  arow = (size_t)gr;
        else if (UP)  arow = (size_t)list[e * T_TOK + cr];
        else          arow = (size_t)(obase + cr);
        pA = Ap + arow * ASTRr + kk;
    }
#pragma unroll
    for (int u = 0; u < 2; ++u) {
        int c = u * 512 + tid, s = c >> 3, sl = (c & 7) ^ (s & 7);
        int rB = 2 * s + (sl >> 2), kk = (sl & 3) * 8;
        const unsigned short* p = Bp + (size_t)(bx * 256 + rB) * BSTRr + kk;
        if (u == 0) pB0 = p; else pB1 = p;
    }

    f32x4 acc[4][4];
#pragma unroll
    for (int m = 0; m < 4; ++m)
#pragma unroll
        for (int n = 0; n < 4; ++n) acc[m][n] = (f32x4)0.f;

    gload16(pA,      (void*)(smem + 0 + d16));
    gload16(pA + 32, (void*)(smem + 8192 + d16));
    gload16(pB0,      (void*)(smem + 24576 + d16));
    gload16(pB1,      (void*)(smem + 24576 + 8192 + d16));
    gload16(pB0 + 32, (void*)(smem + 24576 + 16384 + d16));
    gload16(pB1 + 32, (void*)(smem + 24576 + 16384 + 8192 + d16));
    pA += 64; pB0 += 64; pB1 += 64;
    asm volatile("s_waitcnt vmcnt(0)" ::: "memory");
    __builtin_amdgcn_s_barrier();

    int bA = 0, bA2 = 16384;
    int bB = 0, bB2 = 32768;
    for (int t = 0; t < NT; ++t) {
        short8 aF[4], bF[4];
#pragma unroll
        for (int m = 0; m < 4; ++m)
            aF[m] = *(const short8*)(smem + bA + wm * 4096 + m * 1024 + offR);
#pragma unroll
        for (int n = 0; n < 4; ++n)
            bF[n] = *(const short8*)(smem + 24576 + bB + wn * 4096 + n * 1024 + offR);
        const bool more = (t + 2 < NT);
        if (more) {
            gload16(pA, (void*)(smem + bA2 + d16));
            gload16(pB0, (void*)(smem + 24576 + bB2 + d16));
            gload16(pB1, (void*)(smem + 24576 + bB2 + 8192 + d16));
            pA += 32; pB0 += 32; pB1 += 32;
        }
        __builtin_amdgcn_s_setprio(1);
#pragma unroll
        for (int m = 0; m < 4; ++m)
#pragma unroll
            for (int n = 0; n < 4; ++n)
                acc[m][n] = __builtin_amdgcn_mfma_f32_16x16x32_bf16(aF[m], bF[n], acc[m][n], 0, 0, 0);
        __builtin_amdgcn_s_setprio(0);
        if (more) { asm volatile("s_waitcnt vmcnt(3)" ::: "memory"); }
        else      { asm volatile("s_waitcnt vmcnt(0)" ::: "memory"); }
        __builtin_amdgcn_s_barrier();
        bA = (bA == 16384) ? 0 : bA + 8192;
        bA2 = (bA2 == 16384) ? 0 : bA2 + 8192;
        bB = (bB == 32768) ? 0 : bB + 16384;
        bB2 = (bB2 == 32768) ? 0 : bB2 + 16384;
    }

    if constexpr (UP) {
        const int LDO = routed ? NI : NSH;
        unsigned short* hp = routed ? hbuf : hs;
#pragma unroll
        for (int m = 0; m < 4; ++m)
#pragma unroll
            for (int q = 0; q < 4; ++q) {
                int gr = rb + wm * 64 + m * 16 + fq * 4 + q;
                if (gr < M) {
                    float coef = routed ? cw[e * T_TOK + gr] : 1.f;
                    size_t orow = (size_t)((routed ? obase : 0) + gr) * LDO;
#pragma unroll
                    for (int nfp = 0; nfp < 2; ++nfp) {
                        float c1 = acc[m][2 * nfp][q], c3 = acc[m][2 * nfp + 1][q];
                        float h = c1 / (1.f + __expf(-c1)) * c3 * coef;
                        int ncol = (bx * 8 + wn * 2 + nfp) * 16 + fr;
                        hp[orow + ncol] = f2bf(h);
                    }
                }
            }
    } else {
#pragma unroll
        for (int m = 0; m < 4; ++m)
#pragma unroll
            for (int q = 0; q < 4; ++q) {
                int gr = rb + wm * 64 + m * 16 + fq * 4 + q;
                if (gr < M) {
                    if (routed) {
                        unsigned short* op = dbuf + (size_t)(obase + gr) * DIMD;
#pragma unroll
                        for (int nf = 0; nf < 4; ++nf) {
                            int col = bx * 256 + wn * 64 + nf * 16 + fr;
                            op[col] = f2bf(acc[m][nf][q]);
                        }
                    } else {
                        float* op = fout + (size_t)gr * DIMD;
#pragma unroll
                        for (int nf = 0; nf < 4; ++nf) {
                            int col = bx * 256 + wn * 64 + nf * 16 + fr;
                            op[col] = acc[m][nf][q];
                        }
                    }
                }
            }
    }
}

extern "C" void kernel_launch(void* const* d_in, const int* in_sizes, int n_in,
                              void* d_out, int out_size, void* d_ws, size_t ws_size,
                              hipStream_t stream) {
    const float* x   = (const float*)d_in[0];
    const float* gw  = (const float*)d_in[1];
    const float* w1  = (const float*)d_in[2];
    const float* w2  = (const float*)d_in[3];
    const float* w3  = (const float*)d_in[4];
    const float* ws1 = (const float*)d_in[5];
    const float* ws2 = (const float*)d_in[6];
    const float* ws3 = (const float*)d_in[7];
    float* out = (float*)d_out;

    char* p = (char*)d_ws;
    unsigned short* xb   = (unsigned short*)p; p += (size_t)T_TOK * DIMD * 2;
    unsigned short* hs   = (unsigned short*)p; p += (size_t)T_TOK * NSH * 2;
    unsigned short* hbuf = (unsigned short*)p; p += (size_t)T_TOK * TOPK * NI * 2;
    unsigned short* upT  = (unsigned short*)p; p += (size_t)NEXP * 2048 * DIMD * 2;
    unsigned short* w2T  = (unsigned short*)p; p += (size_t)NEXP * DIMD * NI * 2;
    unsigned short* upsT = (unsigned short*)p; p += (size_t)2 * NSH * DIMD * 2;
    unsigned short* ws2T = (unsigned short*)p; p += (size_t)DIMD * NSH * 2;
    float* gwT = (float*)p;                    p += (size_t)NEXP * DIMD * 4;
    float* cw = (float*)p;                     p += (size_t)NEXP * T_TOK * 4;
    int* list = (int*)p;                       p += (size_t)NEXP * T_TOK * 4;
    int* tk_er = (int*)p;                      p += (size_t)T_TOK * TOPK * 4;
    float* tk_wv = (float*)p;                  p += (size_t)T_TOK * TOPK * 4;
    int* rows = (int*)p;                       p += (size_t)T_TOK * TOPK * 4;
    int* blk_cnt = (int*)p;                    p += (size_t)1024 * 16 * 4;
    int* blk_off = (int*)p;                    p += (size_t)1024 * 16 * 4;
    int* cnt = (int*)p;                        p += 256;
    int* offs = (int*)p;                       p += 256;
    int* table = (int*)p;                      p += 4096 * 4;
    if ((size_t)(p - (char*)d_ws) > ws_size) return;
    // dbuf (bf16, 67MB) aliases upT (134MB, dead after fused-up)
    unsigned short* dbuf = upT;

    hipFuncSetAttribute((const void*)&gemm_f<true>, hipFuncAttributeMaxDynamicSharedMemorySize, 73728);
    hipFuncSetAttribute((const void*)&gemm_f<false>, hipFuncAttributeMaxDynamicSharedMemorySize, 73728);

    gwt_kernel<<<(NEXP * DIMD) / 256, 256, 0, stream>>>(gw, gwT);
    gate_kernel<<<T_TOK / 4, 256, 0, stream>>>(x, gwT, blk_cnt, tk_er, tk_wv, xb);
    scan_kernel<<<1, 256, 0, stream>>>(blk_cnt, blk_off, cnt, offs, table);
    fill_kernel<<<T_TOK * TOPK / 256, 256, 0, stream>>>(tk_er, tk_wv, blk_off, offs,
                                                        list, cw, rows);

    tq_pair<<<dim3(NI / 64, DIMD / 64, NEXP), 256, 0, stream>>>(
        w1, w3, upT, DIMD, NI, (size_t)DIMD * NI, (size_t)2048 * DIMD);
    tq_pair<<<dim3(NSH / 64, DIMD / 64, 1), 256, 0, stream>>>(
        ws1, ws3, upsT, DIMD, NSH, 0, 0);
    tq_plain<<<dim3(DIMD / 64, NI / 64, NEXP), 256, 0, stream>>>(
        w2, w2T, NI, DIMD, (size_t)NI * DIMD, (size_t)DIMD * NI);
    tq_plain<<<dim3(DIMD / 64, NSH / 64, 1), 256, 0, stream>>>(
        ws2, ws2T, NSH, DIMD, 0, 0);

    // fused up: [0,512) shared, [512, 512+8*TCAP) routed (XCD-classed table)
    gemm_f<true><<<512 + 8 * TCAP, 512, 73728, stream>>>(
        xb, xb, upsT, upT, cnt, offs, list, cw, hs, hbuf, nullptr, nullptr, table);
    // fused down: [0,256) shared bx-major -> out; [256,...) routed -> bf16 dbuf
    gemm_f<false><<<256 + 8 * TCAP, 512, 73728, stream>>>(
        hs, hbuf, ws2T, w2T, cnt, offs, list, nullptr, nullptr, nullptr, out, dbuf, table);
    // out[t] += sum of 4 routed rows
    gather_kernel<<<T_TOK, 256, 0, stream>>>(dbuf, rows, out);
}

// Round 15
// 585.912 us; speedup vs baseline: 1.2270x; 1.0091x over previous
//
#include <hip/hip_runtime.h>
#include <hip/hip_bf16.h>
#include <stdint.h>

#define T_TOK 4096
#define DIMD  2048
#define NEXP  16
#define TOPK  4
#define NI    1024
#define NSH   2048
#define TCAP  256   // per-XCD-class routed block capacity at BM=256 (exact worst case)

typedef __attribute__((ext_vector_type(8))) short short8;
typedef __attribute__((ext_vector_type(4))) float f32x4;
typedef __attribute__((ext_vector_type(4))) unsigned short u16x4;
typedef __attribute__((ext_vector_type(8))) unsigned short u16x8;

__device__ __forceinline__ unsigned short f2bf(float f) {
    union { float f; unsigned u; } v; v.f = f;
    return (unsigned short)((v.u + 0x7fffu + ((v.u >> 16) & 1u)) >> 16);
}

__device__ __forceinline__ float bf2f(unsigned short b) {
    union { unsigned u; float f; } v; v.u = (unsigned)b << 16;
    return v.f;
}

__device__ __forceinline__ void gload16(const void* g, void* l) {
    __builtin_amdgcn_global_load_lds(
        (const __attribute__((address_space(1))) void*)g,
        (__attribute__((address_space(3))) void*)l, 16, 0, 0);
}

// ---------------- gw transpose ----------------
__global__ __launch_bounds__(256) void gwt_kernel(const float* __restrict__ gw,
                                                  float* __restrict__ gwT) {
    int i = blockIdx.x * 256 + threadIdx.x;
    int d = i >> 4, e = i & 15;
    gwT[e * DIMD + d] = gw[i];
}

// ------- gate: scores + top-4 + LDS-histogram routing + x->bf16 store -------
__global__ __launch_bounds__(256) void gate_kernel(const float* __restrict__ x,
                                                   const float* __restrict__ gwT,
                                                   int* __restrict__ blk_cnt,
                                                   int* __restrict__ tk_er,
                                                   float* __restrict__ tk_wv,
                                                   unsigned short* __restrict__ xb) {
    __shared__ int h[16];
    const int blk = blockIdx.x;
    const int t = blk * 4 + (threadIdx.x >> 6);
    const int lane = threadIdx.x & 63;
    if (threadIdx.x < 16) h[threadIdx.x] = 0;
    __syncthreads();

    const f32x4* xr = (const f32x4*)(x + (size_t)t * DIMD);
    f32x4 xv[8];
#pragma unroll
    for (int i = 0; i < 8; ++i) xv[i] = xr[i * 64 + lane];

    {
        unsigned short* xo = xb + (size_t)t * DIMD;
#pragma unroll
        for (int i = 0; i < 8; ++i) {
            u16x4 o;
#pragma unroll
            for (int j = 0; j < 4; ++j) o[j] = f2bf(xv[i][j]);
            *(u16x4*)(xo + i * 256 + lane * 4) = o;
        }
    }

    float acc[NEXP];
#pragma unroll
    for (int e = 0; e < NEXP; ++e) {
        const f32x4* gr = (const f32x4*)(gwT + e * DIMD);
        float s = 0.f;
#pragma unroll
        for (int i = 0; i < 8; ++i) {
            f32x4 gv = gr[i * 64 + lane];
            s += xv[i][0] * gv[0] + xv[i][1] * gv[1] +
                 xv[i][2] * gv[2] + xv[i][3] * gv[3];
        }
        acc[e] = s;
    }
#pragma unroll
    for (int e = 0; e < NEXP; ++e) {
        float v = acc[e];
#pragma unroll
        for (int off = 32; off; off >>= 1) v += __shfl_xor(v, off, 64);
        acc[e] = v;
    }
    float m = acc[0];
#pragma unroll
    for (int e = 1; e < NEXP; ++e) m = fmaxf(m, acc[e]);
    float s = 0.f;
#pragma unroll
    for (int e = 0; e < NEXP; ++e) { acc[e] = expf(acc[e] - m); s += acc[e]; }
    float inv = 1.f / s;
#pragma unroll
    for (int e = 0; e < NEXP; ++e) acc[e] *= inv;

    float w4[TOPK]; int i4[TOPK];
#pragma unroll
    for (int k = 0; k < TOPK; ++k) {
        float bv = -1.f; int be = 0;
#pragma unroll
        for (int e = 0; e < NEXP; ++e)
            if (acc[e] > bv) { bv = acc[e]; be = e; }
        w4[k] = bv; i4[k] = be;
#pragma unroll
        for (int e = 0; e < NEXP; ++e)
            if (e == be) acc[e] = -1.f;
    }

    if (lane == 0) {
        int r4[TOPK];
#pragma unroll
        for (int k = 0; k < TOPK; ++k) r4[k] = atomicAdd(&h[i4[k]], 1);
#pragma unroll
        for (int k = 0; k < TOPK; ++k) {
            tk_er[t * 4 + k] = (i4[k] << 20) | r4[k];
            tk_wv[t * 4 + k] = w4[k];
        }
    }
    __syncthreads();
    if (threadIdx.x < 16) blk_cnt[blk * 16 + threadIdx.x] = h[threadIdx.x];
}

// ---- hierarchical scan + XCD-class routed block table (BM=256) ----
// table[idx], class c = idx&7 (experts c, c+8): entry = (e<<16)|(bx<<13)|rb, -1 empty.
__global__ __launch_bounds__(256) void scan_kernel(const int* __restrict__ blk_cnt,
                                                   int* __restrict__ blk_off,
                                                   int* __restrict__ cnt,
                                                   int* __restrict__ offs,
                                                   int* __restrict__ table) {
    __shared__ int gsum[16][17];
    __shared__ int gbase[16][17];
    __shared__ int csh[16];
    int tid = threadIdx.x;
    int e = tid >> 4, g = tid & 15;
    {
        int s = 0;
        for (int b = g * 64; b < g * 64 + 64; ++b) s += blk_cnt[b * 16 + e];
        gsum[e][g] = s;
    }
    __syncthreads();
    if (tid < 16) {
        int run = 0;
        for (int g2 = 0; g2 < 16; ++g2) { gbase[tid][g2] = run; run += gsum[tid][g2]; }
        csh[tid] = run;
        cnt[tid] = run;
    }
    __syncthreads();
    {
        int run = gbase[e][g];
        for (int b = g * 64; b < g * 64 + 64; ++b) {
            blk_off[b * 16 + e] = run;
            run += blk_cnt[b * 16 + e];
        }
    }
    if (tid == 0) {
        int o = 0;
        for (int e2 = 0; e2 < 16; ++e2) { offs[e2] = o; o += csh[e2]; }
        offs[NEXP] = o;
    }
    __syncthreads();
    for (int idx = tid; idx < 8 * TCAP; idx += 256) {
        int c = idx & 7, j = idx >> 3;
        int n0 = ((csh[c] + 255) >> 8) << 3;
        int n1 = ((csh[c + 8] + 255) >> 8) << 3;
        int v = -1;
        if (j < n0)
            v = (c << 16) | ((j & 7) << 13) | ((j >> 3) * 256);
        else if (j < n0 + n1) {
            int j2 = j - n0;
            v = ((c + 8) << 16) | ((j2 & 7) << 13) | ((j2 >> 3) * 256);
        }
        table[idx] = v;
    }
}

// ---------------- fill compacted expert lists + token->row table ----------------
__global__ __launch_bounds__(256) void fill_kernel(const int* __restrict__ tk_er,
                                                   const float* __restrict__ tk_wv,
                                                   const int* __restrict__ blk_off,
                                                   const int* __restrict__ offs,
                                                   int* __restrict__ list,
                                                   float* __restrict__ cw,
                                                   int* __restrict__ rows) {
    int i = blockIdx.x * 256 + threadIdx.x;
    int rec = tk_er[i];
    int e = rec >> 20, r = rec & 0xFFFFF;
    int t = i >> 2;
    int ro = blk_off[(t >> 2) * 16 + e] + r;
    list[e * T_TOK + ro] = t;
    cw[e * T_TOK + ro] = tk_wv[i];
    rows[i] = offs[e] + ro;
}

// ---------------- weight transpose+convert: 64x64 tiles, 16B stores ----------------
__global__ __launch_bounds__(256) void tq_pair(const float* __restrict__ s1,
                                               const float* __restrict__ s3,
                                               unsigned short* __restrict__ dst,
                                               int K, int N,
                                               size_t srcStrideE, size_t dstStrideE) {
    int e = blockIdx.z;
    s1 += (size_t)e * srcStrideE;
    s3 += (size_t)e * srcStrideE;
    dst += (size_t)e * dstStrideE;
    __shared__ unsigned short tile[64][72];
    const int t = threadIdx.x;
    const int k0 = blockIdx.y * 64, n0 = blockIdx.x * 64;
    const int lr = t >> 4, lc4 = (t & 15) * 4;
    const int sr8 = (t & 7) * 8, sn = t >> 3;
#pragma unroll
    for (int half = 0; half < 2; ++half) {
        const float* src = half ? s3 : s1;
#pragma unroll
        for (int r = 0; r < 4; ++r) {
            f32x4 v = *(const f32x4*)(src + (size_t)(k0 + lr + r * 16) * N + n0 + lc4);
#pragma unroll
            for (int j = 0; j < 4; ++j) tile[lr + r * 16][lc4 + j] = f2bf(v[j]);
        }
        __syncthreads();
#pragma unroll
        for (int q = 0; q < 2; ++q) {
            int nn = sn + q * 32;
            int n = n0 + nn;
            int rrow = (n >> 4) * 32 + half * 16 + (n & 15);
            u16x8 o;
#pragma unroll
            for (int j = 0; j < 8; ++j) o[j] = tile[sr8 + j][nn];
            *(u16x8*)(dst + (size_t)rrow * K + k0 + sr8) = o;
        }
        __syncthreads();
    }
}

__global__ __launch_bounds__(256) void tq_plain(const float* __restrict__ src,
                                                unsigned short* __restrict__ dst,
                                                int K, int N,
                                                size_t srcStrideE, size_t dstStrideE) {
    int e = blockIdx.z;
    src += (size_t)e * srcStrideE;
    dst += (size_t)e * dstStrideE;
    __shared__ unsigned short tile[64][72];
    const int t = threadIdx.x;
    const int k0 = blockIdx.y * 64, n0 = blockIdx.x * 64;
    const int lr = t >> 4, lc4 = (t & 15) * 4;
    const int sr8 = (t & 7) * 8, sn = t >> 3;
#pragma unroll
    for (int r = 0; r < 4; ++r) {
        f32x4 v = *(const f32x4*)(src + (size_t)(k0 + lr + r * 16) * N + n0 + lc4);
#pragma unroll
        for (int j = 0; j < 4; ++j) tile[lr + r * 16][lc4 + j] = f2bf(v[j]);
    }
    __syncthreads();
#pragma unroll
    for (int q = 0; q < 2; ++q) {
        int nn = sn + q * 32;
        int n = n0 + nn;
        u16x8 o;
#pragma unroll
        for (int j = 0; j < 8; ++j) o[j] = tile[sr8 + j][nn];
        *(u16x8*)(dst + (size_t)n * K + k0 + sr8) = o;
    }
}

// ---------------- gather: out[t] += sum of 4 routed rows (bf16 dbuf) ----------------
__global__ __launch_bounds__(256) void gather_kernel(const unsigned short* __restrict__ dbuf,
                                                     const int* __restrict__ rows,
                                                     float* __restrict__ out) {
    const int t = blockIdx.x;
    const int c8 = threadIdx.x * 8;
    int r[4];
#pragma unroll
    for (int k = 0; k < 4; ++k) r[k] = rows[t * 4 + k];
    f32x4 a0, a1;
    {
        const f32x4* z = (const f32x4*)(out + (size_t)t * DIMD + c8);
        a0 = z[0]; a1 = z[1];
    }
#pragma unroll
    for (int k = 0; k < 4; ++k) {
        u16x8 d = *(const u16x8*)(dbuf + (size_t)r[k] * DIMD + c8);
#pragma unroll
        for (int j = 0; j < 4; ++j) { a0[j] += bf2f(d[j]); a1[j] += bf2f(d[4 + j]); }
    }
    f32x4* o = (f32x4*)(out + (size_t)t * DIMD + c8);
    o[0] = a0; o[1] = a1;
}

// ========== 256x256 BK=64 8-phase GEMM (m201-faithful port) ==========
// 8 waves (2M x 4N), wave tile 128x64. LDS 128KB: A = d*32768 + h*16384 (h = M-half),
// B same +65536. Swizzle: 16B-slot ^= row&7 (pre-swizzled source, swizzled read).
// Per K-tile (4 phases = C-quadrants (0,0),(0,1),(1,1),(1,0)):
//   P0: read A(mh0) 8 + B(nh0) 4, stage Bh1(t+1) | P1: read B(nh1) 4, stage Ah1(t+1)
//   P2: read A(mh1) 8, stage Bh0(t+2)            | P3: no reads, stage Ah0(t+2), vmcnt(4)
// Each phase: [reads; stage; barrier; lgkmcnt(0)+sched_barrier; setprio1; 16 MFMA; setprio0; barrier]

#define BAR __builtin_amdgcn_s_barrier()
#define LGKM0 do { asm volatile("s_waitcnt lgkmcnt(0)" ::: "memory"); \
                   __builtin_amdgcn_sched_barrier(0); } while (0)

#define SA(H, D, KT) do { \
    gload16(pA[H][0] + (KT) * 64, (void*)(smem + (D) * 32768 + dofs[H][0])); \
    gload16(pA[H][1] + (KT) * 64, (void*)(smem + (D) * 32768 + dofs[H][1])); \
  } while (0)
#define SB(H, D, KT) do { \
    gload16(pB[H][0] + (KT) * 64, (void*)(smem + 65536 + (D) * 32768 + dofs[H][0])); \
    gload16(pB[H][1] + (KT) * 64, (void*)(smem + 65536 + (D) * 32768 + dofs[H][1])); \
  } while (0)

#define RDA(MH, D) do { \
    _Pragma("unroll") \
    for (int m2 = 0; m2 < 4; ++m2) { \
      const char* bp = smem + (D) * 32768 + wm * 16384 + ((MH) * 64 + m2 * 16 + fr) * 128; \
      aF[m2][0] = *(const short8*)(bp + kA0); \
      aF[m2][1] = *(const short8*)(bp + kA1); \
    } } while (0)
#define RDB(dst, NH, D) do { \
    _Pragma("unroll") \
    for (int n2 = 0; n2 < 2; ++n2) { \
      const char* bp = smem + 65536 + (D) * 32768 + (wn >> 1) * 16384 + \
                       ((wn & 1) * 64 + (NH) * 32 + n2 * 16 + fr) * 128; \
      dst[n2][0] = *(const short8*)(bp + kA0); \
      dst[n2][1] = *(const short8*)(bp + kA1); \
    } } while (0)

#define MM(MH, NH, BF) do { \
    __builtin_amdgcn_s_setprio(1); \
    _Pragma("unroll") \
    for (int m2 = 0; m2 < 4; ++m2) { \
      _Pragma("unroll") \
      for (int n2 = 0; n2 < 2; ++n2) { \
        acc[(MH) * 4 + m2][(NH) * 2 + n2] = __builtin_amdgcn_mfma_f32_16x16x32_bf16( \
            aF[m2][0], BF[n2][0], acc[(MH) * 4 + m2][(NH) * 2 + n2], 0, 0, 0); \
        acc[(MH) * 4 + m2][(NH) * 2 + n2] = __builtin_amdgcn_mfma_f32_16x16x32_bf16( \
            aF[m2][1], BF[n2][1], acc[(MH) * 4 + m2][(NH) * 2 + n2], 0, 0, 0); \
      } \
    } \
    __builtin_amdgcn_s_setprio(0); \
  } while (0)

template <bool UP>
__global__ __launch_bounds__(512, 2) void gemm_f(
    const unsigned short* __restrict__ Ash, const unsigned short* __restrict__ Art,
    const unsigned short* __restrict__ Bsh, const unsigned short* __restrict__ Brt,
    const int* __restrict__ cnt, const int* __restrict__ offs,
    const int* __restrict__ list, const float* __restrict__ cw,
    unsigned short* __restrict__ hs, unsigned short* __restrict__ hbuf,
    float* __restrict__ fout, unsigned short* __restrict__ dbuf,
    const int* __restrict__ table) {
    constexpr int SHBLK = UP ? 256 : 128;

    const int bid = blockIdx.x;
    const bool routed = bid >= SHBLK;
    int bx, rb, e = 0, M, obase = 0;
    const unsigned short* Ap;
    const unsigned short* Bp;
    int ASTRr, BSTRr;
    if (!routed) {
        if (UP) { bx = bid & 15; rb = (bid >> 4) * 256; }
        else    { bx = bid >> 4; rb = (bid & 15) * 256; }   // bx-major: same-rb co-XCD
        M = T_TOK;
        Ap = Ash; Bp = Bsh;
        ASTRr = 2048; BSTRr = 2048;
    } else {
        int pk = table[bid - SHBLK];   // (bid-SHBLK)%8 == e%8 == XCD class
        if (pk < 0) return;
        e = pk >> 16; bx = (pk >> 13) & 7; rb = pk & 8191;
        M = cnt[e]; obase = offs[e];
        Ap = Art;
        Bp = Brt + (UP ? (size_t)e * 2048 * 2048 : (size_t)e * 2048 * 1024);
        ASTRr = UP ? 2048 : 1024;
        BSTRr = UP ? 2048 : 1024;
    }
    const int NT = UP ? 32 : (routed ? 16 : 32);

    extern __shared__ char smem[];

    const int tid = threadIdx.x;
    const int lane = tid & 63, wid = tid >> 6;
    const int wm = wid >> 2, wn = wid & 3;          // wave tile 128x64
    const int fr = lane & 15, fq = lane >> 4;
    const int s7 = fr & 7;
    const int kA0 = ((fq ^ s7) << 4);
    const int kA1 = kA0 ^ 64;

    // staging maps: half h, load i; dest linear, source pre-swizzled
    const unsigned short* pA[2][2];
    const unsigned short* pB[2][2];
    int dofs[2][2];
#pragma unroll
    for (int h = 0; h < 2; ++h)
#pragma unroll
        for (int i = 0; i < 2; ++i) {
            int c = i * 512 + tid;
            int lr = c >> 3;
            int lsl = (c & 7) ^ (lr & 7);
            dofs[h][i] = h * 16384 + c * 16;
            int grA = rb + h * 128 + lr;
            int crA = (grA < M) ? grA : (M - 1);
            size_t arow;
            if (!routed)  arow = (size_t)grA;
            else if (UP)  arow = (size_t)list[e * T_TOK + crA];
            else          arow = (size_t)(obase + crA);
            pA[h][i] = Ap + arow * ASTRr + lsl * 8;
            pB[h][i] = Bp + (size_t)(bx * 256 + h * 128 + lr) * BSTRr + lsl * 8;
        }

    f32x4 acc[8][4];
#pragma unroll
    for (int m = 0; m < 8; ++m)
#pragma unroll
        for (int n = 0; n < 4; ++n) acc[m][n] = (f32x4)0.f;

    short8 aF[4][2], bF0[2][2], bF1[2][2];

    // prologue: tile0 full (buf0) + tile1 Bh0, Ah0 (buf1) = 12 loads
    SB(0, 0, 0); SB(1, 0, 0); SA(0, 0, 0); SA(1, 0, 0);
    SB(0, 1, 1); SA(0, 1, 1);
    asm volatile("s_waitcnt vmcnt(4)" ::: "memory");
    BAR;

    for (int t = 0; t < NT; ++t) {
        const int D = t & 1;
        const bool m1 = (t + 1 < NT), m2g = (t + 2 < NT);
        // P0: quad(0,0)
        RDA(0, D); RDB(bF0, 0, D);
        if (m1) SB(1, D ^ 1, t + 1);
        BAR; LGKM0;
        MM(0, 0, bF0);
        BAR;
        // P1: quad(0,1)
        RDB(bF1, 1, D);
        if (m1) SA(1, D ^ 1, t + 1);
        BAR; LGKM0;
        MM(0, 1, bF1);
        BAR;
        // P2: quad(1,1)
        RDA(1, D);
        if (m2g) SB(0, D, t + 2);
        BAR; LGKM0;
        MM(1, 1, bF1);
        BAR;
        // P3: quad(1,0) — no reads
        if (m2g) SA(0, D, t + 2);
        MM(1, 0, bF0);
        if (m1) {
            if (m2g) { asm volatile("s_waitcnt vmcnt(4)" ::: "memory"); }
            else     { asm volatile("s_waitcnt vmcnt(0)" ::: "memory"); }
        }
        BAR;
    }

    // epilogue
    if constexpr (UP) {
        const int LDO = routed ? NI : NSH;
        unsigned short* hp = routed ? hbuf : hs;
#pragma unroll
        for (int m = 0; m < 8; ++m)
#pragma unroll
            for (int q = 0; q < 4; ++q) {
                int gr = rb + wm * 128 + (m >> 2) * 64 + (m & 3) * 16 + fq * 4 + q;
                if (gr < M) {
                    float coef = routed ? cw[e * T_TOK + gr] : 1.f;
                    size_t orow = (size_t)((routed ? obase : 0) + gr) * LDO;
#pragma unroll
                    for (int j = 0; j < 2; ++j) {
                        float c1 = acc[m][2 * j][q], c3 = acc[m][2 * j + 1][q];
                        float hv = c1 / (1.f + __expf(-c1)) * c3 * coef;
                        int ncol = (bx * 8 + wn * 2 + j) * 16 + fr;
                        hp[orow + ncol] = f2bf(hv);
                    }
                }
            }
    } else {
#pragma unroll
        for (int m = 0; m < 8; ++m)
#pragma unroll
            for (int q = 0; q < 4; ++q) {
                int gr = rb + wm * 128 + (m >> 2) * 64 + (m & 3) * 16 + fq * 4 + q;
                if (gr < M) {
                    if (routed) {
                        unsigned short* op = dbuf + (size_t)(obase + gr) * DIMD;
#pragma unroll
                        for (int n = 0; n < 4; ++n) {
                            int col = bx * 256 + wn * 64 + (n >> 1) * 32 + (n & 1) * 16 + fr;
                            op[col] = f2bf(acc[m][n][q]);
                        }
                    } else {
                        float* op = fout + (size_t)gr * DIMD;
#pragma unroll
                        for (int n = 0; n < 4; ++n) {
                            int col = bx * 256 + wn * 64 + (n >> 1) * 32 + (n & 1) * 16 + fr;
                            op[col] = acc[m][n][q];
                        }
                    }
                }
            }
    }
}

extern "C" void kernel_launch(void* const* d_in, const int* in_sizes, int n_in,
                              void* d_out, int out_size, void* d_ws, size_t ws_size,
                              hipStream_t stream) {
    const float* x   = (const float*)d_in[0];
    const float* gw  = (const float*)d_in[1];
    const float* w1  = (const float*)d_in[2];
    const float* w2  = (const float*)d_in[3];
    const float* w3  = (const float*)d_in[4];
    const float* ws1 = (const float*)d_in[5];
    const float* ws2 = (const float*)d_in[6];
    const float* ws3 = (const float*)d_in[7];
    float* out = (float*)d_out;

    char* p = (char*)d_ws;
    unsigned short* xb   = (unsigned short*)p; p += (size_t)T_TOK * DIMD * 2;
    unsigned short* hs   = (unsigned short*)p; p += (size_t)T_TOK * NSH * 2;
    unsigned short* hbuf = (unsigned short*)p; p += (size_t)T_TOK * TOPK * NI * 2;
    unsigned short* upT  = (unsigned short*)p; p += (size_t)NEXP * 2048 * DIMD * 2;
    unsigned short* w2T  = (unsigned short*)p; p += (size_t)NEXP * DIMD * NI * 2;
    unsigned short* upsT = (unsigned short*)p; p += (size_t)2 * NSH * DIMD * 2;
    unsigned short* ws2T = (unsigned short*)p; p += (size_t)DIMD * NSH * 2;
    float* gwT = (float*)p;                    p += (size_t)NEXP * DIMD * 4;
    float* cw = (float*)p;                     p += (size_t)NEXP * T_TOK * 4;
    int* list = (int*)p;                       p += (size_t)NEXP * T_TOK * 4;
    int* tk_er = (int*)p;                      p += (size_t)T_TOK * TOPK * 4;
    float* tk_wv = (float*)p;                  p += (size_t)T_TOK * TOPK * 4;
    int* rows = (int*)p;                       p += (size_t)T_TOK * TOPK * 4;
    int* blk_cnt = (int*)p;                    p += (size_t)1024 * 16 * 4;
    int* blk_off = (int*)p;                    p += (size_t)1024 * 16 * 4;
    int* cnt = (int*)p;                        p += 256;
    int* offs = (int*)p;                       p += 256;
    int* table = (int*)p;                      p += 8192 * 4;
    if ((size_t)(p - (char*)d_ws) > ws_size) return;
    // dbuf (bf16, 67MB) aliases upT (134MB, dead after fused-up)
    unsigned short* dbuf = upT;

    hipFuncSetAttribute((const void*)&gemm_f<true>, hipFuncAttributeMaxDynamicSharedMemorySize, 131072);
    hipFuncSetAttribute((const void*)&gemm_f<false>, hipFuncAttributeMaxDynamicSharedMemorySize, 131072);

    gwt_kernel<<<(NEXP * DIMD) / 256, 256, 0, stream>>>(gw, gwT);
    gate_kernel<<<T_TOK / 4, 256, 0, stream>>>(x, gwT, blk_cnt, tk_er, tk_wv, xb);
    scan_kernel<<<1, 256, 0, stream>>>(blk_cnt, blk_off, cnt, offs, table);
    fill_kernel<<<T_TOK * TOPK / 256, 256, 0, stream>>>(tk_er, tk_wv, blk_off, offs,
                                                        list, cw, rows);

    tq_pair<<<dim3(NI / 64, DIMD / 64, NEXP), 256, 0, stream>>>(
        w1, w3, upT, DIMD, NI, (size_t)DIMD * NI, (size_t)2048 * DIMD);
    tq_pair<<<dim3(NSH / 64, DIMD / 64, 1), 256, 0, stream>>>(
        ws1, ws3, upsT, DIMD, NSH, 0, 0);
    tq_plain<<<dim3(DIMD / 64, NI / 64, NEXP), 256, 0, stream>>>(
        w2, w2T, NI, DIMD, (size_t)NI * DIMD, (size_t)DIMD * NI);
    tq_plain<<<dim3(DIMD / 64, NSH / 64, 1), 256, 0, stream>>>(
        ws2, ws2T, NSH, DIMD, 0, 0);

    // fused up: [0,256) shared (16 bx x 16 rb), [256,...) routed (XCD-classed table)
    gemm_f<true><<<256 + 8 * TCAP, 512, 131072, stream>>>(
        xb, xb, upsT, upT, cnt, offs, list, cw, hs, hbuf, nullptr, nullptr, table);
    // fused down: [0,128) shared bx-major -> out; [128,...) routed -> bf16 dbuf
    gemm_f<false><<<128 + 8 * TCAP, 512, 131072, stream>>>(
        hs, hbuf, ws2T, w2T, cnt, offs, list, nullptr, nullptr, nullptr, out, dbuf, table);
    // out[t] += sum of 4 routed rows
    gather_kernel<<<T_TOK, 256, 0, stream>>>(dbuf, rows, out);
}

// Round 16
// 584.709 us; speedup vs baseline: 1.2296x; 1.0021x over previous
//
#include <hip/hip_runtime.h>
#include <hip/hip_bf16.h>
#include <stdint.h>

#define T_TOK 4096
#define DIMD  2048
#define NEXP  16
#define TOPK  4
#define NI    1024
#define NSH   2048
#define TCAPU 320   // up table capacity per class (BM=128)
#define TCAPD 256   // down table capacity per class (BM=256)

typedef __attribute__((ext_vector_type(8))) short short8;
typedef __attribute__((ext_vector_type(4))) float f32x4;
typedef __attribute__((ext_vector_type(4))) unsigned short u16x4;
typedef __attribute__((ext_vector_type(8))) unsigned short u16x8;

__device__ __forceinline__ unsigned short f2bf(float f) {
    union { float f; unsigned u; } v; v.f = f;
    return (unsigned short)((v.u + 0x7fffu + ((v.u >> 16) & 1u)) >> 16);
}

__device__ __forceinline__ float bf2f(unsigned short b) {
    union { unsigned u; float f; } v; v.u = (unsigned)b << 16;
    return v.f;
}

__device__ __forceinline__ void gload16(const void* g, void* l) {
    __builtin_amdgcn_global_load_lds(
        (const __attribute__((address_space(1))) void*)g,
        (__attribute__((address_space(3))) void*)l, 16, 0, 0);
}

// ---------------- gw transpose ----------------
__global__ __launch_bounds__(256) void gwt_kernel(const float* __restrict__ gw,
                                                  float* __restrict__ gwT) {
    int i = blockIdx.x * 256 + threadIdx.x;
    int d = i >> 4, e = i & 15;
    gwT[e * DIMD + d] = gw[i];
}

// ------- gate: scores + top-4 + LDS-histogram routing + x->bf16 store -------
__global__ __launch_bounds__(256) void gate_kernel(const float* __restrict__ x,
                                                   const float* __restrict__ gwT,
                                                   int* __restrict__ blk_cnt,
                                                   int* __restrict__ tk_er,
                                                   float* __restrict__ tk_wv,
                                                   unsigned short* __restrict__ xb) {
    __shared__ int h[16];
    const int blk = blockIdx.x;
    const int t = blk * 4 + (threadIdx.x >> 6);
    const int lane = threadIdx.x & 63;
    if (threadIdx.x < 16) h[threadIdx.x] = 0;
    __syncthreads();

    const f32x4* xr = (const f32x4*)(x + (size_t)t * DIMD);
    f32x4 xv[8];
#pragma unroll
    for (int i = 0; i < 8; ++i) xv[i] = xr[i * 64 + lane];

    {
        unsigned short* xo = xb + (size_t)t * DIMD;
#pragma unroll
        for (int i = 0; i < 8; ++i) {
            u16x4 o;
#pragma unroll
            for (int j = 0; j < 4; ++j) o[j] = f2bf(xv[i][j]);
            *(u16x4*)(xo + i * 256 + lane * 4) = o;
        }
    }

    float acc[NEXP];
#pragma unroll
    for (int e = 0; e < NEXP; ++e) {
        const f32x4* gr = (const f32x4*)(gwT + e * DIMD);
        float s = 0.f;
#pragma unroll
        for (int i = 0; i < 8; ++i) {
            f32x4 gv = gr[i * 64 + lane];
            s += xv[i][0] * gv[0] + xv[i][1] * gv[1] +
                 xv[i][2] * gv[2] + xv[i][3] * gv[3];
        }
        acc[e] = s;
    }
#pragma unroll
    for (int e = 0; e < NEXP; ++e) {
        float v = acc[e];
#pragma unroll
        for (int off = 32; off; off >>= 1) v += __shfl_xor(v, off, 64);
        acc[e] = v;
    }
    float m = acc[0];
#pragma unroll
    for (int e = 1; e < NEXP; ++e) m = fmaxf(m, acc[e]);
    float s = 0.f;
#pragma unroll
    for (int e = 0; e < NEXP; ++e) { acc[e] = expf(acc[e] - m); s += acc[e]; }
    float inv = 1.f / s;
#pragma unroll
    for (int e = 0; e < NEXP; ++e) acc[e] *= inv;

    float w4[TOPK]; int i4[TOPK];
#pragma unroll
    for (int k = 0; k < TOPK; ++k) {
        float bv = -1.f; int be = 0;
#pragma unroll
        for (int e = 0; e < NEXP; ++e)
            if (acc[e] > bv) { bv = acc[e]; be = e; }
        w4[k] = bv; i4[k] = be;
#pragma unroll
        for (int e = 0; e < NEXP; ++e)
            if (e == be) acc[e] = -1.f;
    }

    if (lane == 0) {
        int r4[TOPK];
#pragma unroll
        for (int k = 0; k < TOPK; ++k) r4[k] = atomicAdd(&h[i4[k]], 1);
#pragma unroll
        for (int k = 0; k < TOPK; ++k) {
            tk_er[t * 4 + k] = (i4[k] << 20) | r4[k];
            tk_wv[t * 4 + k] = w4[k];
        }
    }
    __syncthreads();
    if (threadIdx.x < 16) blk_cnt[blk * 16 + threadIdx.x] = h[threadIdx.x];
}

// ---- hierarchical scan + XCD-class tables: table_u (BM=128), table_d (BM=256) ----
// entry = (e<<16)|(bx<<13)|rb, -1 empty; class c = idx&7 covers experts c, c+8.
__global__ __launch_bounds__(256) void scan_kernel(const int* __restrict__ blk_cnt,
                                                   int* __restrict__ blk_off,
                                                   int* __restrict__ cnt,
                                                   int* __restrict__ offs,
                                                   int* __restrict__ table_u,
                                                   int* __restrict__ table_d) {
    __shared__ int gsum[16][17];
    __shared__ int gbase[16][17];
    __shared__ int csh[16];
    int tid = threadIdx.x;
    int e = tid >> 4, g = tid & 15;
    {
        int s = 0;
        for (int b = g * 64; b < g * 64 + 64; ++b) s += blk_cnt[b * 16 + e];
        gsum[e][g] = s;
    }
    __syncthreads();
    if (tid < 16) {
        int run = 0;
        for (int g2 = 0; g2 < 16; ++g2) { gbase[tid][g2] = run; run += gsum[tid][g2]; }
        csh[tid] = run;
        cnt[tid] = run;
    }
    __syncthreads();
    {
        int run = gbase[e][g];
        for (int b = g * 64; b < g * 64 + 64; ++b) {
            blk_off[b * 16 + e] = run;
            run += blk_cnt[b * 16 + e];
        }
    }
    if (tid == 0) {
        int o = 0;
        for (int e2 = 0; e2 < 16; ++e2) { offs[e2] = o; o += csh[e2]; }
        offs[NEXP] = o;
    }
    __syncthreads();
    for (int idx = tid; idx < 8 * TCAPU; idx += 256) {
        int c = idx & 7, j = idx >> 3;
        int n0 = ((csh[c] + 127) >> 7) << 3;
        int n1 = ((csh[c + 8] + 127) >> 7) << 3;
        int v = -1;
        if (j < n0)
            v = (c << 16) | ((j & 7) << 13) | ((j >> 3) * 128);
        else if (j < n0 + n1) {
            int j2 = j - n0;
            v = ((c + 8) << 16) | ((j2 & 7) << 13) | ((j2 >> 3) * 128);
        }
        table_u[idx] = v;
    }
    for (int idx = tid; idx < 8 * TCAPD; idx += 256) {
        int c = idx & 7, j = idx >> 3;
        int n0 = ((csh[c] + 255) >> 8) << 3;
        int n1 = ((csh[c + 8] + 255) >> 8) << 3;
        int v = -1;
        if (j < n0)
            v = (c << 16) | ((j & 7) << 13) | ((j >> 3) * 256);
        else if (j < n0 + n1) {
            int j2 = j - n0;
            v = ((c + 8) << 16) | ((j2 & 7) << 13) | ((j2 >> 3) * 256);
        }
        table_d[idx] = v;
    }
}

// ---------------- fill compacted expert lists + token->row table ----------------
__global__ __launch_bounds__(256) void fill_kernel(const int* __restrict__ tk_er,
                                                   const float* __restrict__ tk_wv,
                                                   const int* __restrict__ blk_off,
                                                   const int* __restrict__ offs,
                                                   int* __restrict__ list,
                                                   float* __restrict__ cw,
                                                   int* __restrict__ rows) {
    int i = blockIdx.x * 256 + threadIdx.x;
    int rec = tk_er[i];
    int e = rec >> 20, r = rec & 0xFFFFF;
    int t = i >> 2;
    int ro = blk_off[(t >> 2) * 16 + e] + r;
    list[e * T_TOK + ro] = t;
    cw[e * T_TOK + ro] = tk_wv[i];
    rows[i] = offs[e] + ro;
}

// ---------------- weight transpose+convert: 64x64 tiles, 16B stores ----------------
__global__ __launch_bounds__(256) void tq_pair(const float* __restrict__ s1,
                                               const float* __restrict__ s3,
                                               unsigned short* __restrict__ dst,
                                               int K, int N,
                                               size_t srcStrideE, size_t dstStrideE) {
    int e = blockIdx.z;
    s1 += (size_t)e * srcStrideE;
    s3 += (size_t)e * srcStrideE;
    dst += (size_t)e * dstStrideE;
    __shared__ unsigned short tile[64][72];
    const int t = threadIdx.x;
    const int k0 = blockIdx.y * 64, n0 = blockIdx.x * 64;
    const int lr = t >> 4, lc4 = (t & 15) * 4;
    const int sr8 = (t & 7) * 8, sn = t >> 3;
#pragma unroll
    for (int half = 0; half < 2; ++half) {
        const float* src = half ? s3 : s1;
#pragma unroll
        for (int r = 0; r < 4; ++r) {
            f32x4 v = *(const f32x4*)(src + (size_t)(k0 + lr + r * 16) * N + n0 + lc4);
#pragma unroll
            for (int j = 0; j < 4; ++j) tile[lr + r * 16][lc4 + j] = f2bf(v[j]);
        }
        __syncthreads();
#pragma unroll
        for (int q = 0; q < 2; ++q) {
            int nn = sn + q * 32;
            int n = n0 + nn;
            int rrow = (n >> 4) * 32 + half * 16 + (n & 15);
            u16x8 o;
#pragma unroll
            for (int j = 0; j < 8; ++j) o[j] = tile[sr8 + j][nn];
            *(u16x8*)(dst + (size_t)rrow * K + k0 + sr8) = o;
        }
        __syncthreads();
    }
}

__global__ __launch_bounds__(256) void tq_plain(const float* __restrict__ src,
                                                unsigned short* __restrict__ dst,
                                                int K, int N,
                                                size_t srcStrideE, size_t dstStrideE) {
    int e = blockIdx.z;
    src += (size_t)e * srcStrideE;
    dst += (size_t)e * dstStrideE;
    __shared__ unsigned short tile[64][72];
    const int t = threadIdx.x;
    const int k0 = blockIdx.y * 64, n0 = blockIdx.x * 64;
    const int lr = t >> 4, lc4 = (t & 15) * 4;
    const int sr8 = (t & 7) * 8, sn = t >> 3;
#pragma unroll
    for (int r = 0; r < 4; ++r) {
        f32x4 v = *(const f32x4*)(src + (size_t)(k0 + lr + r * 16) * N + n0 + lc4);
#pragma unroll
        for (int j = 0; j < 4; ++j) tile[lr + r * 16][lc4 + j] = f2bf(v[j]);
    }
    __syncthreads();
#pragma unroll
    for (int q = 0; q < 2; ++q) {
        int nn = sn + q * 32;
        int n = n0 + nn;
        u16x8 o;
#pragma unroll
        for (int j = 0; j < 8; ++j) o[j] = tile[sr8 + j][nn];
        *(u16x8*)(dst + (size_t)n * K + k0 + sr8) = o;
    }
}

// ---------------- gather: out[t] += sum of 4 routed rows (bf16 dbuf) ----------------
__global__ __launch_bounds__(256) void gather_kernel(const unsigned short* __restrict__ dbuf,
                                                     const int* __restrict__ rows,
                                                     float* __restrict__ out) {
    const int t = blockIdx.x;
    const int c8 = threadIdx.x * 8;
    int r[4];
#pragma unroll
    for (int k = 0; k < 4; ++k) r[k] = rows[t * 4 + k];
    f32x4 a0, a1;
    {
        const f32x4* z = (const f32x4*)(out + (size_t)t * DIMD + c8);
        a0 = z[0]; a1 = z[1];
    }
#pragma unroll
    for (int k = 0; k < 4; ++k) {
        u16x8 d = *(const u16x8*)(dbuf + (size_t)r[k] * DIMD + c8);
#pragma unroll
        for (int j = 0; j < 4; ++j) { a0[j] += bf2f(d[j]); a1[j] += bf2f(d[4 + j]); }
    }
    f32x4* o = (f32x4*)(out + (size_t)t * DIMD + c8);
    o[0] = a0; o[1] = a1;
}

// ======== UP GEMM (R14 structure): 128x256, BK=32, tri-buffered, 2 blocks/CU ========
// 8 waves (wave tile 64x64). LDS 72KB: A 3x8KB @0, B 3x16KB @24576. vmcnt(3), 1 barrier/tile.
// Superrow swizzle: s=r>>1, slot=((r&1)<<2)|(k>>3); phys = s*128+((slot^(s&7))<<4)+(k&7)*2.
__global__ __launch_bounds__(512, 2) void gemm_up(
    const unsigned short* __restrict__ xb, const unsigned short* __restrict__ upsT,
    const unsigned short* __restrict__ upT,
    const int* __restrict__ cnt, const int* __restrict__ offs,
    const int* __restrict__ list, const float* __restrict__ cw,
    unsigned short* __restrict__ hs, unsigned short* __restrict__ hbuf,
    const int* __restrict__ table) {
    constexpr int SHBLK = 512;
    constexpr int NT = 64;

    const int bid = blockIdx.x;
    const bool routed = bid >= SHBLK;
    int bx, rb, e = 0, M, obase = 0;
    const unsigned short* Bp;
    if (!routed) {
        bx = bid & 15; rb = (bid >> 4) * 128;
        M = T_TOK;
        Bp = upsT;
    } else {
        int pk = table[bid - SHBLK];
        if (pk < 0) return;
        e = pk >> 16; bx = (pk >> 13) & 7; rb = pk & 8191;
        M = cnt[e]; obase = offs[e];
        Bp = upT + (size_t)e * 2048 * 2048;
    }

    extern __shared__ char smem[];

    const int tid = threadIdx.x;
    const int lane = tid & 63, wid = tid >> 6;
    const int wm = wid >> 2, wn = wid & 3;
    const int fr = lane & 15, fq = lane >> 4;
    const int offR = ((fr >> 1) << 7) + (((((fr & 1) << 2) | fq) ^ (fr >> 1)) << 4);
    const int d16 = tid * 16;

    const unsigned short* pA;
    const unsigned short* pB0;
    const unsigned short* pB1;
    {
        int c = tid, s = c >> 3, sl = (c & 7) ^ (s & 7);
        int rA = 2 * s + (sl >> 2), kk = (sl & 3) * 8;
        int gr = rb + rA;
        int cr = (gr < M) ? gr : (M - 1);
        size_t arow = routed ? (size_t)list[e * T_TOK + cr] : (size_t)gr;
        pA = xb + arow * 2048 + kk;
    }
#pragma unroll
    for (int u = 0; u < 2; ++u) {
        int c = u * 512 + tid, s = c >> 3, sl = (c & 7) ^ (s & 7);
        int rB = 2 * s + (sl >> 2), kk = (sl & 3) * 8;
        const unsigned short* p = Bp + (size_t)(bx * 256 + rB) * 2048 + kk;
        if (u == 0) pB0 = p; else pB1 = p;
    }

    f32x4 acc[4][4];
#pragma unroll
    for (int m = 0; m < 4; ++m)
#pragma unroll
        for (int n = 0; n < 4; ++n) acc[m][n] = (f32x4)0.f;

    gload16(pA,      (void*)(smem + 0 + d16));
    gload16(pA + 32, (void*)(smem + 8192 + d16));
    gload16(pB0,      (void*)(smem + 24576 + d16));
    gload16(pB1,      (void*)(smem + 24576 + 8192 + d16));
    gload16(pB0 + 32, (void*)(smem + 24576 + 16384 + d16));
    gload16(pB1 + 32, (void*)(smem + 24576 + 16384 + 8192 + d16));
    pA += 64; pB0 += 64; pB1 += 64;
    asm volatile("s_waitcnt vmcnt(0)" ::: "memory");
    __builtin_amdgcn_s_barrier();

    int bA = 0, bA2 = 16384;
    int bB = 0, bB2 = 32768;
    for (int t = 0; t < NT; ++t) {
        short8 aF[4], bF[4];
#pragma unroll
        for (int m = 0; m < 4; ++m)
            aF[m] = *(const short8*)(smem + bA + wm * 4096 + m * 1024 + offR);
#pragma unroll
        for (int n = 0; n < 4; ++n)
            bF[n] = *(const short8*)(smem + 24576 + bB + wn * 4096 + n * 1024 + offR);
        const bool more = (t + 2 < NT);
        if (more) {
            gload16(pA, (void*)(smem + bA2 + d16));
            gload16(pB0, (void*)(smem + 24576 + bB2 + d16));
            gload16(pB1, (void*)(smem + 24576 + bB2 + 8192 + d16));
            pA += 32; pB0 += 32; pB1 += 32;
        }
        __builtin_amdgcn_s_setprio(1);
#pragma unroll
        for (int m = 0; m < 4; ++m)
#pragma unroll
            for (int n = 0; n < 4; ++n)
                acc[m][n] = __builtin_amdgcn_mfma_f32_16x16x32_bf16(aF[m], bF[n], acc[m][n], 0, 0, 0);
        __builtin_amdgcn_s_setprio(0);
        if (more) { asm volatile("s_waitcnt vmcnt(3)" ::: "memory"); }
        else      { asm volatile("s_waitcnt vmcnt(0)" ::: "memory"); }
        __builtin_amdgcn_s_barrier();
        bA = (bA == 16384) ? 0 : bA + 8192;
        bA2 = (bA2 == 16384) ? 0 : bA2 + 8192;
        bB = (bB == 32768) ? 0 : bB + 16384;
        bB2 = (bB2 == 32768) ? 0 : bB2 + 16384;
    }

    const int LDO = routed ? NI : NSH;
    unsigned short* hp = routed ? hbuf : hs;
#pragma unroll
    for (int m = 0; m < 4; ++m)
#pragma unroll
        for (int q = 0; q < 4; ++q) {
            int gr = rb + wm * 64 + m * 16 + fq * 4 + q;
            if (gr < M) {
                float coef = routed ? cw[e * T_TOK + gr] : 1.f;
                size_t orow = (size_t)((routed ? obase : 0) + gr) * LDO;
#pragma unroll
                for (int nfp = 0; nfp < 2; ++nfp) {
                    float c1 = acc[m][2 * nfp][q], c3 = acc[m][2 * nfp + 1][q];
                    float h = c1 / (1.f + __expf(-c1)) * c3 * coef;
                    int ncol = (bx * 8 + wn * 2 + nfp) * 16 + fr;
                    hp[orow + ncol] = f2bf(h);
                }
            }
        }
}

// ======== DOWN GEMM (R15 structure): 256x256, BK=64, 8-phase, 1 block/CU ========
#define BAR __builtin_amdgcn_s_barrier()
#define LGKM0 do { asm volatile("s_waitcnt lgkmcnt(0)" ::: "memory"); \
                   __builtin_amdgcn_sched_barrier(0); } while (0)

#define SA(H, D, KT) do { \
    gload16(pA[H][0] + (KT) * 64, (void*)(smem + (D) * 32768 + dofs[H][0])); \
    gload16(pA[H][1] + (KT) * 64, (void*)(smem + (D) * 32768 + dofs[H][1])); \
  } while (0)
#define SB(H, D, KT) do { \
    gload16(pB[H][0] + (KT) * 64, (void*)(smem + 65536 + (D) * 32768 + dofs[H][0])); \
    gload16(pB[H][1] + (KT) * 64, (void*)(smem + 65536 + (D) * 32768 + dofs[H][1])); \
  } while (0)

#define RDA(MH, D) do { \
    _Pragma("unroll") \
    for (int m2 = 0; m2 < 4; ++m2) { \
      const char* bp = smem + (D) * 32768 + wm * 16384 + ((MH) * 64 + m2 * 16 + fr) * 128; \
      aF[m2][0] = *(const short8*)(bp + kA0); \
      aF[m2][1] = *(const short8*)(bp + kA1); \
    } } while (0)
#define RDB(dst, NH, D) do { \
    _Pragma("unroll") \
    for (int n2 = 0; n2 < 2; ++n2) { \
      const char* bp = smem + 65536 + (D) * 32768 + (wn >> 1) * 16384 + \
                       ((wn & 1) * 64 + (NH) * 32 + n2 * 16 + fr) * 128; \
      dst[n2][0] = *(const short8*)(bp + kA0); \
      dst[n2][1] = *(const short8*)(bp + kA1); \
    } } while (0)

#define MM(MH, NH, BF) do { \
    __builtin_amdgcn_s_setprio(1); \
    _Pragma("unroll") \
    for (int m2 = 0; m2 < 4; ++m2) { \
      _Pragma("unroll") \
      for (int n2 = 0; n2 < 2; ++n2) { \
        acc[(MH) * 4 + m2][(NH) * 2 + n2] = __builtin_amdgcn_mfma_f32_16x16x32_bf16( \
            aF[m2][0], BF[n2][0], acc[(MH) * 4 + m2][(NH) * 2 + n2], 0, 0, 0); \
        acc[(MH) * 4 + m2][(NH) * 2 + n2] = __builtin_amdgcn_mfma_f32_16x16x32_bf16( \
            aF[m2][1], BF[n2][1], acc[(MH) * 4 + m2][(NH) * 2 + n2], 0, 0, 0); \
      } \
    } \
    __builtin_amdgcn_s_setprio(0); \
  } while (0)

__global__ __launch_bounds__(512, 2) void gemm_dn(
    const unsigned short* __restrict__ hsA, const unsigned short* __restrict__ hbufA,
    const unsigned short* __restrict__ ws2T, const unsigned short* __restrict__ w2T,
    const int* __restrict__ cnt, const int* __restrict__ offs,
    const int* __restrict__ list,
    float* __restrict__ fout, unsigned short* __restrict__ dbuf,
    const int* __restrict__ table) {
    constexpr int SHBLK = 128;

    const int bid = blockIdx.x;
    const bool routed = bid >= SHBLK;
    int bx, rb, e = 0, M, obase = 0;
    const unsigned short* Ap;
    const unsigned short* Bp;
    int ASTRr, BSTRr;
    if (!routed) {
        bx = bid >> 4; rb = (bid & 15) * 256;
        M = T_TOK;
        Ap = hsA; Bp = ws2T;
        ASTRr = 2048; BSTRr = 2048;
    } else {
        int pk = table[bid - SHBLK];
        if (pk < 0) return;
        e = pk >> 16; bx = (pk >> 13) & 7; rb = pk & 8191;
        M = cnt[e]; obase = offs[e];
        Ap = hbufA;
        Bp = w2T + (size_t)e * 2048 * 1024;
        ASTRr = 1024; BSTRr = 1024;
    }
    const int NT = routed ? 16 : 32;

    extern __shared__ char smem[];

    const int tid = threadIdx.x;
    const int lane = tid & 63, wid = tid >> 6;
    const int wm = wid >> 2, wn = wid & 3;
    const int fr = lane & 15, fq = lane >> 4;
    const int s7 = fr & 7;
    const int kA0 = ((fq ^ s7) << 4);
    const int kA1 = kA0 ^ 64;

    const unsigned short* pA[2][2];
    const unsigned short* pB[2][2];
    int dofs[2][2];
#pragma unroll
    for (int h = 0; h < 2; ++h)
#pragma unroll
        for (int i = 0; i < 2; ++i) {
            int c = i * 512 + tid;
            int lr = c >> 3;
            int lsl = (c & 7) ^ (lr & 7);
            dofs[h][i] = h * 16384 + c * 16;
            int grA = rb + h * 128 + lr;
            int crA = (grA < M) ? grA : (M - 1);
            size_t arow = routed ? (size_t)(obase + crA) : (size_t)grA;
            pA[h][i] = Ap + arow * ASTRr + lsl * 8;
            pB[h][i] = Bp + (size_t)(bx * 256 + h * 128 + lr) * BSTRr + lsl * 8;
        }

    f32x4 acc[8][4];
#pragma unroll
    for (int m = 0; m < 8; ++m)
#pragma unroll
        for (int n = 0; n < 4; ++n) acc[m][n] = (f32x4)0.f;

    short8 aF[4][2], bF0[2][2], bF1[2][2];

    SB(0, 0, 0); SB(1, 0, 0); SA(0, 0, 0); SA(1, 0, 0);
    SB(0, 1, 1); SA(0, 1, 1);
    asm volatile("s_waitcnt vmcnt(4)" ::: "memory");
    BAR;

    for (int t = 0; t < NT; ++t) {
        const int D = t & 1;
        const bool m1 = (t + 1 < NT), m2g = (t + 2 < NT);
        RDA(0, D); RDB(bF0, 0, D);
        if (m1) SB(1, D ^ 1, t + 1);
        BAR; LGKM0;
        MM(0, 0, bF0);
        BAR;
        RDB(bF1, 1, D);
        if (m1) SA(1, D ^ 1, t + 1);
        BAR; LGKM0;
        MM(0, 1, bF1);
        BAR;
        RDA(1, D);
        if (m2g) SB(0, D, t + 2);
        BAR; LGKM0;
        MM(1, 1, bF1);
        BAR;
        if (m2g) SA(0, D, t + 2);
        MM(1, 0, bF0);
        if (m1) {
            if (m2g) { asm volatile("s_waitcnt vmcnt(4)" ::: "memory"); }
            else     { asm volatile("s_waitcnt vmcnt(0)" ::: "memory"); }
        }
        BAR;
    }

#pragma unroll
    for (int m = 0; m < 8; ++m)
#pragma unroll
        for (int q = 0; q < 4; ++q) {
            int gr = rb + wm * 128 + (m >> 2) * 64 + (m & 3) * 16 + fq * 4 + q;
            if (gr < M) {
                if (routed) {
                    unsigned short* op = dbuf + (size_t)(obase + gr) * DIMD;
#pragma unroll
                    for (int n = 0; n < 4; ++n) {
                        int col = bx * 256 + wn * 64 + (n >> 1) * 32 + (n & 1) * 16 + fr;
                        op[col] = f2bf(acc[m][n][q]);
                    }
                } else {
                    float* op = fout + (size_t)gr * DIMD;
#pragma unroll
                    for (int n = 0; n < 4; ++n) {
                        int col = bx * 256 + wn * 64 + (n >> 1) * 32 + (n & 1) * 16 + fr;
                        op[col] = acc[m][n][q];
                    }
                }
            }
        }
}

extern "C" void kernel_launch(void* const* d_in, const int* in_sizes, int n_in,
                              void* d_out, int out_size, void* d_ws, size_t ws_size,
                              hipStream_t stream) {
    const float* x   = (const float*)d_in[0];
    const float* gw  = (const float*)d_in[1];
    const float* w1  = (const float*)d_in[2];
    const float* w2  = (const float*)d_in[3];
    const float* w3  = (const float*)d_in[4];
    const float* ws1 = (const float*)d_in[5];
    const float* ws2 = (const float*)d_in[6];
    const float* ws3 = (const float*)d_in[7];
    float* out = (float*)d_out;

    char* p = (char*)d_ws;
    unsigned short* xb   = (unsigned short*)p; p += (size_t)T_TOK * DIMD * 2;
    unsigned short* hs   = (unsigned short*)p; p += (size_t)T_TOK * NSH * 2;
    unsigned short* hbuf = (unsigned short*)p; p += (size_t)T_TOK * TOPK * NI * 2;
    unsigned short* upT  = (unsigned short*)p; p += (size_t)NEXP * 2048 * DIMD * 2;
    unsigned short* w2T  = (unsigned short*)p; p += (size_t)NEXP * DIMD * NI * 2;
    unsigned short* upsT = (unsigned short*)p; p += (size_t)2 * NSH * DIMD * 2;
    unsigned short* ws2T = (unsigned short*)p; p += (size_t)DIMD * NSH * 2;
    float* gwT = (float*)p;                    p += (size_t)NEXP * DIMD * 4;
    float* cw = (float*)p;                     p += (size_t)NEXP * T_TOK * 4;
    int* list = (int*)p;                       p += (size_t)NEXP * T_TOK * 4;
    int* tk_er = (int*)p;                      p += (size_t)T_TOK * TOPK * 4;
    float* tk_wv = (float*)p;                  p += (size_t)T_TOK * TOPK * 4;
    int* rows = (int*)p;                       p += (size_t)T_TOK * TOPK * 4;
    int* blk_cnt = (int*)p;                    p += (size_t)1024 * 16 * 4;
    int* blk_off = (int*)p;                    p += (size_t)1024 * 16 * 4;
    int* cnt = (int*)p;                        p += 256;
    int* offs = (int*)p;                       p += 256;
    int* table_u = (int*)p;                    p += 8 * TCAPU * 4;
    int* table_d = (int*)p;                    p += 8 * TCAPD * 4;
    if ((size_t)(p - (char*)d_ws) > ws_size) return;
    // dbuf (bf16, 67MB) aliases upT (134MB, dead after gemm_up)
    unsigned short* dbuf = upT;

    hipFuncSetAttribute((const void*)&gemm_up, hipFuncAttributeMaxDynamicSharedMemorySize, 73728);
    hipFuncSetAttribute((const void*)&gemm_dn, hipFuncAttributeMaxDynamicSharedMemorySize, 131072);

    gwt_kernel<<<(NEXP * DIMD) / 256, 256, 0, stream>>>(gw, gwT);
    gate_kernel<<<T_TOK / 4, 256, 0, stream>>>(x, gwT, blk_cnt, tk_er, tk_wv, xb);
    scan_kernel<<<1, 256, 0, stream>>>(blk_cnt, blk_off, cnt, offs, table_u, table_d);
    fill_kernel<<<T_TOK * TOPK / 256, 256, 0, stream>>>(tk_er, tk_wv, blk_off, offs,
                                                        list, cw, rows);

    tq_pair<<<dim3(NI / 64, DIMD / 64, NEXP), 256, 0, stream>>>(
        w1, w3, upT, DIMD, NI, (size_t)DIMD * NI, (size_t)2048 * DIMD);
    tq_pair<<<dim3(NSH / 64, DIMD / 64, 1), 256, 0, stream>>>(
        ws1, ws3, upsT, DIMD, NSH, 0, 0);
    tq_plain<<<dim3(DIMD / 64, NI / 64, NEXP), 256, 0, stream>>>(
        w2, w2T, NI, DIMD, (size_t)NI * DIMD, (size_t)DIMD * NI);
    tq_plain<<<dim3(DIMD / 64, NSH / 64, 1), 256, 0, stream>>>(
        ws2, ws2T, NSH, DIMD, 0, 0);

    // up (R14 structure): [0,512) shared, [512,...) routed (BM=128 table)
    gemm_up<<<512 + 8 * TCAPU, 512, 73728, stream>>>(
        xb, upsT, upT, cnt, offs, list, cw, hs, hbuf, table_u);
    // down (R15 structure): [0,128) shared bx-major -> out; [128,...) routed -> bf16 dbuf
    gemm_dn<<<128 + 8 * TCAPD, 512, 131072, stream>>>(
        hs, hbuf, ws2T, w2T, cnt, offs, list, out, dbuf, table_d);
    // out[t] += sum of 4 routed rows
    gather_kernel<<<T_TOK, 256, 0, stream>>>(dbuf, rows, out);
}